// Round 2
// baseline (5295.581 us; speedup 1.0000x reference)
//
#include <hip/hip_runtime.h>
#include <math.h>

#define Bb 16
#define Ls 8192
#define Dm 128
#define NBK 6
#define Nst 32
#define NCl 16
#define Em 256
#define LC 256
#define NCH 32   // Ls / LC

__device__ __forceinline__ float geluf(float x) {
    float x3 = x * x * x;
    float t = tanhf(fmaf(0.0356774081f, x3, 0.7978845608f * x));
    return 0.5f * x * (1.f + t);
}
__device__ __forceinline__ float sigmf(float x) { return 1.f / (1.f + expf(-x)); }

// ---------------- conv: h[b,d,l] = sum_k x[b,l-2+k]*w[d,k] + b[d] ----------------
__global__ void s4e_conv(const float* __restrict__ x, const float* __restrict__ cw,
                         const float* __restrict__ cb, float* __restrict__ h) {
    int idx = blockIdx.x * 256 + threadIdx.x;        // over B*D*L
    int l = idx & (Ls - 1);
    int bd = idx >> 13;
    int d = bd & (Dm - 1);
    int b = bd >> 7;
    const float* xb = x + (size_t)b * Ls;
    float acc = cb[d];
#pragma unroll
    for (int k = 0; k < 5; ++k) {
        int p = l + k - 2;
        float xv = (p >= 0 && p < Ls) ? xb[p] : 0.f;
        acc = fmaf(cw[d * 5 + k], xv, acc);
    }
    h[idx] = acc;
}

// ---------------- channel LayerNorm: z[b,:,l] = LN(h[b,:,l]) * w + b ----------------
__global__ void s4e_ln(const float* __restrict__ h, const float* __restrict__ w,
                       const float* __restrict__ bb, float* __restrict__ z) {
    __shared__ float t[Dm * 64];
    __shared__ float ps[4 * 64], pq[4 * 64];
    __shared__ float mu[64], rs[64];
    int b = blockIdx.x >> 7;
    int l0 = (blockIdx.x & 127) << 6;
    const float* hb = h + (size_t)b * Dm * Ls + l0;
    for (int i = threadIdx.x; i < Dm * 64; i += 256) {
        int d = i >> 6, j = i & 63;
        t[i] = hb[(size_t)d * Ls + j];
    }
    __syncthreads();
    int l = threadIdx.x & 63, part = threadIdx.x >> 6;
    float s = 0.f, q = 0.f;
#pragma unroll 4
    for (int dd = 0; dd < 32; ++dd) {
        float v = t[(part * 32 + dd) * 64 + l];
        s += v; q += v * v;
    }
    ps[part * 64 + l] = s; pq[part * 64 + l] = q;
    __syncthreads();
    if (threadIdx.x < 64) {
        float S = 0.f, Q = 0.f;
#pragma unroll
        for (int p = 0; p < 4; ++p) { S += ps[p * 64 + l]; Q += pq[p * 64 + l]; }
        float m = S * (1.f / Dm);
        float v = Q * (1.f / Dm) - m * m;
        mu[l] = m; rs[l] = rsqrtf(v + 1e-5f);
    }
    __syncthreads();
    float* zb = z + (size_t)b * Dm * Ls + l0;
    for (int i = threadIdx.x; i < Dm * 64; i += 256) {
        int d = i >> 6, j = i & 63;
        zb[(size_t)d * Ls + j] = (t[i] - mu[j]) * rs[j] * w[d] + bb[d];
    }
}

// ---------------- per-block S4 param setup: w = exp(dtA), w^LC, C' = C*(w-1)/A ----------------
__global__ void s4e_setup(const float* __restrict__ log_dt, const float* __restrict__ lAr,
                          const float* __restrict__ Aim, const float* __restrict__ Cre,
                          const float* __restrict__ Cim, float2* __restrict__ wv,
                          float2* __restrict__ wp, float2* __restrict__ Cc) {
    int d = threadIdx.x;   // 128 threads
    float dt = expf(log_dt[d]);
    for (int n = 0; n < Nst; ++n) {
        int id = d * Nst + n;
        float Ar = -expf(lAr[id]);
        float Ai = Aim[id];
        float xr = dt * Ar, xi = dt * Ai;
        float er = expf(xr);
        float wr = er * cosf(xi), wi = er * sinf(xi);
        wv[id] = make_float2(wr, wi);
        float den = Ar * Ar + Ai * Ai;
        float inv = 1.f / den;
        float fr = ((wr - 1.f) * Ar + wi * Ai) * inv;
        float fi = (wi * Ar - (wr - 1.f) * Ai) * inv;
        Cc[id] = make_float2(Cre[id] * fr - Cim[id] * fi, Cre[id] * fi + Cim[id] * fr);
        float pr = wr, pi = wi;
#pragma unroll
        for (int sq = 0; sq < 8; ++sq) {     // w^(2^8) = w^256 = w^LC
            float nr = pr * pr - pi * pi;
            float ni = 2.f * pr * pi;
            pr = nr; pi = ni;
        }
        wp[id] = make_float2(pr, pi);
    }
}

// ---------------- S1: per-chunk local end states ----------------
__global__ __launch_bounds__(256) void s4e_s1(const float* __restrict__ z,
        const float2* __restrict__ wv, float2* __restrict__ send) {
    int tid = blockIdx.x * 256 + threadIdx.x;   // B*D*NCH
    int c = tid & 31;
    int d = (tid >> 5) & 127;
    int b = tid >> 12;
    const float2* w = wv + d * Nst;
    float wr[Nst], wi[Nst], sr[Nst], si[Nst];
#pragma unroll
    for (int n = 0; n < Nst; ++n) { float2 t = w[n]; wr[n] = t.x; wi[n] = t.y; sr[n] = 0.f; si[n] = 0.f; }
    const float* zp = z + (size_t)(b * Dm + d) * Ls + c * LC;
#pragma unroll 1
    for (int j = 0; j < LC; j += 4) {
        float4 zz = *(const float4*)(zp + j);
        float zs[4] = {zz.x, zz.y, zz.z, zz.w};
#pragma unroll
        for (int u = 0; u < 4; ++u) {
            float zv = zs[u];
#pragma unroll
            for (int n = 0; n < Nst; ++n) {
                float t = fmaf(-wi[n], si[n], zv);
                float nr = fmaf(wr[n], sr[n], t);
                float ni = fmaf(wi[n], sr[n], wr[n] * si[n]);
                sr[n] = nr; si[n] = ni;
            }
        }
    }
    float2* o = send + ((size_t)(b * Dm + d) * NCH + c) * Nst;
#pragma unroll
    for (int n = 0; n < Nst; ++n) o[n] = make_float2(sr[n], si[n]);
}

// ---------------- S2: cross-chunk prefix  S_{c+1} = w^LC * S_c + E_c ----------------
__global__ void s4e_s2(const float2* __restrict__ wp, const float2* __restrict__ send,
                       float2* __restrict__ sinit) {
    int tid = blockIdx.x * 256 + threadIdx.x;   // B*D*N
    int n = tid & 31;
    int d = (tid >> 5) & 127;
    int b = tid >> 12;
    float2 W = wp[d * Nst + n];
    float Sr = 0.f, Si = 0.f;
    size_t base = (size_t)(b * Dm + d) * NCH * Nst + n;
    for (int c = 0; c < NCH; ++c) {
        sinit[base + (size_t)c * Nst] = make_float2(Sr, Si);
        float2 E = send[base + (size_t)c * Nst];
        float nr = fmaf(W.x, Sr, fmaf(-W.y, Si, E.x));
        float ni = fmaf(W.x, Si, fmaf(W.y, Sr, E.y));
        Sr = nr; Si = ni;
    }
}

// ---------------- S3: re-scan chunk from corrected init, emit y ----------------
__global__ __launch_bounds__(256) void s4e_s3(const float* __restrict__ z,
        const float2* __restrict__ wv, const float2* __restrict__ Cc,
        const float2* __restrict__ sinit, float* __restrict__ y) {
    int tid = blockIdx.x * 256 + threadIdx.x;
    int c = tid & 31;
    int d = (tid >> 5) & 127;
    int b = tid >> 12;
    const float2* w = wv + d * Nst;
    const float2* C = Cc + d * Nst;
    const float2* s0 = sinit + ((size_t)(b * Dm + d) * NCH + c) * Nst;
    float wr[Nst], wi[Nst], cr[Nst], ci[Nst], sr[Nst], si[Nst];
#pragma unroll
    for (int n = 0; n < Nst; ++n) {
        float2 t = w[n];  wr[n] = t.x; wi[n] = t.y;
        float2 cc = C[n]; cr[n] = cc.x; ci[n] = cc.y;
        float2 ss = s0[n]; sr[n] = ss.x; si[n] = ss.y;
    }
    const float* zp = z + (size_t)(b * Dm + d) * Ls + c * LC;
    float* yp = y + (size_t)(b * Dm + d) * Ls + c * LC;
#pragma unroll 1
    for (int j = 0; j < LC; j += 4) {
        float4 zz = *(const float4*)(zp + j);
        float zs[4] = {zz.x, zz.y, zz.z, zz.w};
        float ys[4];
#pragma unroll
        for (int u = 0; u < 4; ++u) {
            float zv = zs[u];
            float acc = 0.f;
#pragma unroll
            for (int n = 0; n < Nst; ++n) {
                float t = fmaf(-wi[n], si[n], zv);
                float nr = fmaf(wr[n], sr[n], t);
                float ni = fmaf(wi[n], sr[n], wr[n] * si[n]);
                sr[n] = nr; si[n] = ni;
                acc = fmaf(cr[n], nr, acc);
                acc = fmaf(-ci[n], ni, acc);
            }
            ys[u] = 2.f * acc;
        }
        float4 yy; yy.x = ys[0]; yy.y = ys[1]; yy.z = ys[2]; yy.w = ys[3];
        *(float4*)(yp + j) = yy;
    }
}

// ---------------- out-proj + GLU: h += a*sigmoid(g), [a;g] = W*gelu(y+Dsk*z)+bias ----------------
__global__ __launch_bounds__(256) void s4e_outproj(const float* __restrict__ y,
        const float* __restrict__ z, const float* __restrict__ Dsk,
        const float* __restrict__ W, const float* __restrict__ bias,
        float* __restrict__ h) {
    __shared__ float yg[Dm * 32];
    int b = blockIdx.x >> 8;
    int l0 = (blockIdx.x & 255) << 5;
    size_t base = (size_t)b * Dm * Ls + l0;
    for (int i = threadIdx.x; i < Dm * 32; i += 256) {
        int d = i >> 5, j = i & 31;
        float v = y[base + (size_t)d * Ls + j];
        float zv = z[base + (size_t)d * Ls + j];
        yg[i] = geluf(fmaf(Dsk[d], zv, v));
    }
    __syncthreads();
#pragma unroll
    for (int it = 0; it < 4; ++it) {
        int item = it * 256 + threadIdx.x;
        int d = item >> 3, j4 = (item & 7) << 2;
        const float* Wa = W + d * Dm;
        const float* Wg = W + (d + Dm) * Dm;
        float4 aa = {0, 0, 0, 0}, gg = {0, 0, 0, 0};
#pragma unroll 1
        for (int ci = 0; ci < Dm; ci += 4) {
            float4 wa = *(const float4*)(Wa + ci);
            float4 wg = *(const float4*)(Wg + ci);
            float was[4] = {wa.x, wa.y, wa.z, wa.w};
            float wgs[4] = {wg.x, wg.y, wg.z, wg.w};
#pragma unroll
            for (int u = 0; u < 4; ++u) {
                float4 v = *(const float4*)(&yg[(ci + u) * 32 + j4]);
                aa.x = fmaf(was[u], v.x, aa.x); aa.y = fmaf(was[u], v.y, aa.y);
                aa.z = fmaf(was[u], v.z, aa.z); aa.w = fmaf(was[u], v.w, aa.w);
                gg.x = fmaf(wgs[u], v.x, gg.x); gg.y = fmaf(wgs[u], v.y, gg.y);
                gg.z = fmaf(wgs[u], v.z, gg.z); gg.w = fmaf(wgs[u], v.w, gg.w);
            }
        }
        float ba = bias[d], bg = bias[d + Dm];
        float* hp = h + base + (size_t)d * Ls + j4;
        float4 hv = *(float4*)hp;
        hv.x += (aa.x + ba) * sigmf(gg.x + bg);
        hv.y += (aa.y + ba) * sigmf(gg.y + bg);
        hv.z += (aa.z + ba) * sigmf(gg.z + bg);
        hv.w += (aa.w + ba) * sigmf(gg.w + bg);
        *(float4*)hp = hv;
    }
}

// ---------------- fused FF: h += W2 * gelu(W1*z + b1) + b2 (per 32-l tile, via LDS) ----------------
__global__ __launch_bounds__(256) void s4e_ff(const float* __restrict__ z,
        const float* __restrict__ W1, const float* __restrict__ b1,
        const float* __restrict__ W2, const float* __restrict__ b2,
        float* __restrict__ h) {
    __shared__ float zt[Dm * 32];
    __shared__ float et[Em * 32];
    int b = blockIdx.x >> 8;
    int l0 = (blockIdx.x & 255) << 5;
    size_t base = (size_t)b * Dm * Ls + l0;
    for (int i = threadIdx.x; i < Dm * 32; i += 256) {
        int d = i >> 5, j = i & 31;
        zt[i] = z[base + (size_t)d * Ls + j];
    }
    __syncthreads();
#pragma unroll
    for (int it = 0; it < 8; ++it) {
        int item = it * 256 + threadIdx.x;
        int eo = item >> 3, j4 = (item & 7) << 2;
        const float* Wr = W1 + eo * Dm;
        float4 acc = {0, 0, 0, 0};
#pragma unroll 1
        for (int ci = 0; ci < Dm; ci += 4) {
            float4 wq = *(const float4*)(Wr + ci);
            float wqs[4] = {wq.x, wq.y, wq.z, wq.w};
#pragma unroll
            for (int u = 0; u < 4; ++u) {
                float4 v = *(const float4*)(&zt[(ci + u) * 32 + j4]);
                acc.x = fmaf(wqs[u], v.x, acc.x); acc.y = fmaf(wqs[u], v.y, acc.y);
                acc.z = fmaf(wqs[u], v.z, acc.z); acc.w = fmaf(wqs[u], v.w, acc.w);
            }
        }
        float bv = b1[eo];
        float4 r;
        r.x = geluf(acc.x + bv); r.y = geluf(acc.y + bv);
        r.z = geluf(acc.z + bv); r.w = geluf(acc.w + bv);
        *(float4*)(&et[eo * 32 + j4]) = r;
    }
    __syncthreads();
#pragma unroll
    for (int it = 0; it < 4; ++it) {
        int item = it * 256 + threadIdx.x;
        int d = item >> 3, j4 = (item & 7) << 2;
        const float* Wr = W2 + d * Em;
        float4 acc = {0, 0, 0, 0};
#pragma unroll 1
        for (int ci = 0; ci < Em; ci += 4) {
            float4 wq = *(const float4*)(Wr + ci);
            float wqs[4] = {wq.x, wq.y, wq.z, wq.w};
#pragma unroll
            for (int u = 0; u < 4; ++u) {
                float4 v = *(const float4*)(&et[(ci + u) * 32 + j4]);
                acc.x = fmaf(wqs[u], v.x, acc.x); acc.y = fmaf(wqs[u], v.y, acc.y);
                acc.z = fmaf(wqs[u], v.z, acc.z); acc.w = fmaf(wqs[u], v.w, acc.w);
            }
        }
        float bv = b2[d];
        float* hp = h + base + (size_t)d * Ls + j4;
        float4 hv = *(float4*)hp;
        hv.x += acc.x + bv; hv.y += acc.y + bv;
        hv.z += acc.z + bv; hv.w += acc.w + bv;
        *(float4*)hp = hv;
    }
}

// ---------------- head: logits = h[:,:,L-1] @ head_w^T + head_b; argmax ----------------
__global__ void s4e_head(const float* __restrict__ h, const float* __restrict__ hw,
                         const float* __restrict__ hb, int* __restrict__ out) {
    __shared__ float logit[Bb][NCl];
    int tid = threadIdx.x;                // 256 = 16 b * 16 c
    int b = tid >> 4, c = tid & 15;
    float acc = hb[c];
    for (int d = 0; d < Dm; ++d)
        acc = fmaf(h[(size_t)(b * Dm + d) * Ls + (Ls - 1)], hw[c * Dm + d], acc);
    logit[b][c] = acc;
    __syncthreads();
    if (c == 0) {
        float best = logit[b][0]; int bi = 0;
#pragma unroll
        for (int k = 1; k < NCl; ++k) {
            float v = logit[b][k];
            if (v > best) { best = v; bi = k; }
        }
        out[b] = bi;
    }
}

extern "C" void kernel_launch(void* const* d_in, const int* in_sizes, int n_in,
                              void* d_out, int out_size, void* d_ws, size_t ws_size,
                              hipStream_t stream) {
    const float* x        = (const float*)d_in[0];
    const float* conv_w   = (const float*)d_in[1];
    const float* conv_b   = (const float*)d_in[2];
    const float* s4_ln_w  = (const float*)d_in[3];
    const float* s4_ln_b  = (const float*)d_in[4];
    const float* s4_logdt = (const float*)d_in[5];
    const float* s4_lAr   = (const float*)d_in[6];
    const float* s4_Aim   = (const float*)d_in[7];
    const float* s4_Cre   = (const float*)d_in[8];
    const float* s4_Cim   = (const float*)d_in[9];
    const float* s4_D     = (const float*)d_in[10];
    const float* s4_ow    = (const float*)d_in[11];
    const float* s4_ob    = (const float*)d_in[12];
    const float* ff_ln_w  = (const float*)d_in[13];
    const float* ff_ln_b  = (const float*)d_in[14];
    const float* ff_w1    = (const float*)d_in[15];
    const float* ff_b1    = (const float*)d_in[16];
    const float* ff_w2    = (const float*)d_in[17];
    const float* ff_b2    = (const float*)d_in[18];
    const float* head_w   = (const float*)d_in[19];
    const float* head_b   = (const float*)d_in[20];
    int* out = (int*)d_out;

    float* ws = (float*)d_ws;
    float* h  = ws;                      // 16,777,216 floats
    float* z  = ws + 16777216;           // 16,777,216
    float* yv = ws + 33554432;           // 16,777,216
    float2* send  = (float2*)(ws + 50331648);   // 2,097,152 float2
    float2* sinit = (float2*)(ws + 54525952);   // 2,097,152 float2
    float2* wv    = (float2*)(ws + 58720256);   // 4096 float2
    float2* wp    = (float2*)(ws + 58728448);
    float2* Cc    = (float2*)(ws + 58736640);

    s4e_conv<<<Bb * Dm * Ls / 256, 256, 0, stream>>>(x, conv_w, conv_b, h);
    for (int i = 0; i < NBK; ++i) {
        s4e_setup<<<1, 128, 0, stream>>>(s4_logdt + i * Dm, s4_lAr + i * Dm * Nst,
                                         s4_Aim + i * Dm * Nst, s4_Cre + i * Dm * Nst,
                                         s4_Cim + i * Dm * Nst, wv, wp, Cc);
        s4e_ln<<<2048, 256, 0, stream>>>(h, s4_ln_w + i * Dm, s4_ln_b + i * Dm, z);
        s4e_s1<<<256, 256, 0, stream>>>(z, wv, send);
        s4e_s2<<<256, 256, 0, stream>>>(wp, send, sinit);
        s4e_s3<<<256, 256, 0, stream>>>(z, wv, Cc, sinit, yv);
        s4e_outproj<<<4096, 256, 0, stream>>>(yv, z, s4_D + i * Dm,
                                              s4_ow + i * Em * Dm, s4_ob + i * Em, h);
        s4e_ln<<<2048, 256, 0, stream>>>(h, ff_ln_w + i * Dm, ff_ln_b + i * Dm, z);
        s4e_ff<<<4096, 256, 0, stream>>>(z, ff_w1 + i * Em * Dm, ff_b1 + i * Em,
                                         ff_w2 + i * Dm * Em, ff_b2 + i * Dm, h);
    }
    s4e_head<<<1, 256, 0, stream>>>(h, head_w, head_b, out);
}

// Round 3
// 3336.048 us; speedup vs baseline: 1.5874x; 1.5874x over previous
//
#include <hip/hip_runtime.h>
#include <math.h>

#define Bb 16
#define Ls 8192
#define Dm 128
#define NBK 6
#define Nst 32
#define NCl 16
#define Em 256
#define LC 256
#define NCH 32
#define BL (Bb*Ls)

typedef __attribute__((ext_vector_type(8))) short bfrag;   // 8 bf16 (4 VGPRs)
typedef __attribute__((ext_vector_type(4))) float f32x4;

__device__ __forceinline__ float geluf(float x) {
    float x3 = x * x * x;
    float t = tanhf(fmaf(0.0356774081f, x3, 0.7978845608f * x));
    return 0.5f * x * (1.f + t);
}
__device__ __forceinline__ float sigmf(float x) { return 1.f / (1.f + expf(-x)); }

__device__ __forceinline__ unsigned short bf16r(float x) {
    unsigned u = __float_as_uint(x);
    return (unsigned short)((u + 0x7FFFu + ((u >> 16) & 1u)) >> 16);
}
__device__ __forceinline__ void split2(float x, unsigned short& h, unsigned short& l) {
    h = bf16r(x);
    float hf = __uint_as_float(((unsigned)h) << 16);
    l = bf16r(x - hf);
}

// ---------------- conv: h[b,l,d] (token-major) ----------------
__global__ void s4e_conv(const float* __restrict__ x, const float* __restrict__ cw,
                         const float* __restrict__ cb, float* __restrict__ h) {
    int tid = blockIdx.x * 256 + threadIdx.x;     // B*L*32
    int d4 = tid & 31;
    int t = tid >> 5;                             // b*Ls + l
    int l = t & (Ls - 1);
    int b = t >> 13;
    const float* xb = x + (size_t)b * Ls;
    float xs[5];
#pragma unroll
    for (int k = 0; k < 5; ++k) {
        int p = l + k - 2;
        xs[k] = (p >= 0 && p < Ls) ? xb[p] : 0.f;
    }
    float4 acc;
    float* ap = &acc.x;
#pragma unroll
    for (int j = 0; j < 4; ++j) {
        int d = d4 * 4 + j;
        float a = cb[d];
#pragma unroll
        for (int k = 0; k < 5; ++k) a = fmaf(cw[d * 5 + k], xs[k], a);
        ap[j] = a;
    }
    *(float4*)&h[(size_t)t * Dm + d4 * 4] = acc;
}

// ---------------- channel LN (fp32 out): 4 lanes per token ----------------
__global__ void s4e_ln_f32(const float* __restrict__ h, const float* __restrict__ w,
                           const float* __restrict__ bb, float* __restrict__ z) {
    int tid = threadIdx.x;
    int t = blockIdx.x * 64 + (tid >> 2);
    int sub = tid & 3;
    const float* hp = h + (size_t)t * Dm + sub * 32;
    float4 v[8];
    float s = 0.f, q = 0.f;
#pragma unroll
    for (int i = 0; i < 8; ++i) {
        v[i] = *(const float4*)(hp + i * 4);
        s += v[i].x + v[i].y + v[i].z + v[i].w;
        q += v[i].x * v[i].x + v[i].y * v[i].y + v[i].z * v[i].z + v[i].w * v[i].w;
    }
    s += __shfl_xor(s, 1); s += __shfl_xor(s, 2);
    q += __shfl_xor(q, 1); q += __shfl_xor(q, 2);
    float mu = s * (1.f / Dm);
    float rs = rsqrtf(q * (1.f / Dm) - mu * mu + 1e-5f);
    float* zp = z + (size_t)t * Dm + sub * 32;
    const float* wp_ = w + sub * 32;
    const float* bp_ = bb + sub * 32;
#pragma unroll
    for (int i = 0; i < 8; ++i) {
        float4 wv4 = *(const float4*)(wp_ + i * 4);
        float4 bv4 = *(const float4*)(bp_ + i * 4);
        float4 o;
        o.x = (v[i].x - mu) * rs * wv4.x + bv4.x;
        o.y = (v[i].y - mu) * rs * wv4.y + bv4.y;
        o.z = (v[i].z - mu) * rs * wv4.z + bv4.z;
        o.w = (v[i].w - mu) * rs * wv4.w + bv4.w;
        *(float4*)(zp + i * 4) = o;
    }
}

// ---------------- channel LN emitting bf16 hi/lo ----------------
__global__ void s4e_ln_bf(const float* __restrict__ h, const float* __restrict__ w,
                          const float* __restrict__ bb, unsigned short* __restrict__ zh,
                          unsigned short* __restrict__ zl) {
    int tid = threadIdx.x;
    int t = blockIdx.x * 64 + (tid >> 2);
    int sub = tid & 3;
    const float* hp = h + (size_t)t * Dm + sub * 32;
    float4 v[8];
    float s = 0.f, q = 0.f;
#pragma unroll
    for (int i = 0; i < 8; ++i) {
        v[i] = *(const float4*)(hp + i * 4);
        s += v[i].x + v[i].y + v[i].z + v[i].w;
        q += v[i].x * v[i].x + v[i].y * v[i].y + v[i].z * v[i].z + v[i].w * v[i].w;
    }
    s += __shfl_xor(s, 1); s += __shfl_xor(s, 2);
    q += __shfl_xor(q, 1); q += __shfl_xor(q, 2);
    float mu = s * (1.f / Dm);
    float rs = rsqrtf(q * (1.f / Dm) - mu * mu + 1e-5f);
    size_t ob = (size_t)t * Dm + sub * 32;
    const float* wp_ = w + sub * 32;
    const float* bp_ = bb + sub * 32;
#pragma unroll
    for (int i = 0; i < 8; ++i) {
        float4 wv4 = *(const float4*)(wp_ + i * 4);
        float4 bv4 = *(const float4*)(bp_ + i * 4);
        float o0 = (v[i].x - mu) * rs * wv4.x + bv4.x;
        float o1 = (v[i].y - mu) * rs * wv4.y + bv4.y;
        float o2 = (v[i].z - mu) * rs * wv4.z + bv4.z;
        float o3 = (v[i].w - mu) * rs * wv4.w + bv4.w;
        ushort4 hh, ll;
        split2(o0, hh.x, ll.x); split2(o1, hh.y, ll.y);
        split2(o2, hh.z, ll.z); split2(o3, hh.w, ll.w);
        *(ushort4*)&zh[ob + i * 4] = hh;
        *(ushort4*)&zl[ob + i * 4] = ll;
    }
}

// ---------------- S4 params: layouts [n][d] ----------------
__global__ void s4e_setup(const float* __restrict__ log_dt, const float* __restrict__ lAr,
                          const float* __restrict__ Aim, const float* __restrict__ Cre,
                          const float* __restrict__ Cim, float2* __restrict__ wv,
                          float2* __restrict__ wp, float2* __restrict__ Cc) {
    int d = threadIdx.x;
    float dt = expf(log_dt[d]);
    for (int n = 0; n < Nst; ++n) {
        int id = d * Nst + n;
        float Ar = -expf(lAr[id]);
        float Ai = Aim[id];
        float xr = dt * Ar, xi = dt * Ai;
        float er = expf(xr);
        float wr = er * cosf(xi), wi = er * sinf(xi);
        wv[n * Dm + d] = make_float2(wr, wi);
        float den = Ar * Ar + Ai * Ai;
        float inv = 1.f / den;
        float fr = ((wr - 1.f) * Ar + wi * Ai) * inv;
        float fi = (wi * Ar - (wr - 1.f) * Ai) * inv;
        Cc[n * Dm + d] = make_float2(Cre[id] * fr - Cim[id] * fi, Cre[id] * fi + Cim[id] * fr);
        float pr = wr, pi = wi;
#pragma unroll
        for (int sq = 0; sq < 8; ++sq) {
            float nr = pr * pr - pi * pi;
            float ni = 2.f * pr * pi;
            pr = nr; pi = ni;
        }
        wp[n * Dm + d] = make_float2(pr, pi);
    }
}

// ---------------- weight split ----------------
__global__ void s4e_wsplit(const float* __restrict__ ow, const float* __restrict__ w1,
                           const float* __restrict__ w2, unsigned short* __restrict__ base) {
    int idx = blockIdx.x * 256 + threadIdx.x;   // 98304
    int a = idx >> 15, e = idx & 32767;
    const float* src = (a == 0) ? ow : (a == 1) ? w1 : w2;
    float v = src[e];
    unsigned short hh, ll;
    split2(v, hh, ll);
    base[a * 65536 + e] = hh;
    base[a * 65536 + 32768 + e] = ll;
}

// ---------------- S1 ----------------
__global__ __launch_bounds__(256) void s4e_s1(const float* __restrict__ z,
        const float2* __restrict__ wv, float2* __restrict__ send) {
    int tid = blockIdx.x * 256 + threadIdx.x;
    int d = tid & 127;
    int pc = tid >> 7;
    int c = pc & 31, b = pc >> 5;
    float wr[Nst], wi[Nst], sr[Nst], si[Nst];
#pragma unroll
    for (int n = 0; n < Nst; ++n) {
        float2 t = wv[n * Dm + d];
        wr[n] = t.x; wi[n] = t.y; sr[n] = 0.f; si[n] = 0.f;
    }
    const float* zp = z + ((size_t)b * Ls + c * LC) * Dm + d;
#pragma unroll 4
    for (int j = 0; j < LC; ++j) {
        float zv = zp[(size_t)j * Dm];
#pragma unroll
        for (int n = 0; n < Nst; ++n) {
            float t = fmaf(-wi[n], si[n], zv);
            float nr = fmaf(wr[n], sr[n], t);
            float ni = fmaf(wi[n], sr[n], wr[n] * si[n]);
            sr[n] = nr; si[n] = ni;
        }
    }
    float2* o = send + ((size_t)(b * NCH + c) * Nst) * Dm + d;
#pragma unroll
    for (int n = 0; n < Nst; ++n) o[n * Dm] = make_float2(sr[n], si[n]);
}

// ---------------- S2 ----------------
__global__ void s4e_s2(const float2* __restrict__ wp, const float2* __restrict__ send,
                       float2* __restrict__ sinit) {
    int tid = blockIdx.x * 256 + threadIdx.x;
    int d = tid & 127;
    int n = (tid >> 7) & 31;
    int b = tid >> 12;
    float2 W = wp[n * Dm + d];
    float Sr = 0.f, Si = 0.f;
    size_t base = ((size_t)(b * NCH) * Nst + n) * Dm + d;
    for (int c = 0; c < NCH; ++c) {
        size_t ix = base + (size_t)c * Nst * Dm;
        sinit[ix] = make_float2(Sr, Si);
        float2 E = send[ix];
        float nr = fmaf(W.x, Sr, fmaf(-W.y, Si, E.x));
        float ni = fmaf(W.x, Si, fmaf(W.y, Sr, E.y));
        Sr = nr; Si = ni;
    }
}

// ---------------- S3: re-scan + gelu(y + Dsk*z) -> act bf16 hi/lo ----------------
__global__ __launch_bounds__(256) void s4e_s3(const float* __restrict__ z,
        const float2* __restrict__ wv, const float2* __restrict__ Cc,
        const float2* __restrict__ sinit, const float* __restrict__ Dsk,
        unsigned short* __restrict__ acth, unsigned short* __restrict__ actl) {
    int tid = blockIdx.x * 256 + threadIdx.x;
    int d = tid & 127;
    int pc = tid >> 7;
    int c = pc & 31, b = pc >> 5;
    float wr[Nst], wi[Nst], cr[Nst], ci[Nst], sr[Nst], si[Nst];
    const float2* s0 = sinit + ((size_t)(b * NCH + c) * Nst) * Dm + d;
#pragma unroll
    for (int n = 0; n < Nst; ++n) {
        float2 t = wv[n * Dm + d];  wr[n] = t.x; wi[n] = t.y;
        float2 cc = Cc[n * Dm + d]; cr[n] = cc.x; ci[n] = cc.y;
        float2 ss = s0[n * Dm];     sr[n] = ss.x; si[n] = ss.y;
    }
    float Dv = Dsk[d];
    size_t ib = ((size_t)b * Ls + c * LC) * Dm + d;
#pragma unroll 2
    for (int j = 0; j < LC; ++j) {
        float zv = z[ib + (size_t)j * Dm];
        float acc = 0.f;
#pragma unroll
        for (int n = 0; n < Nst; ++n) {
            float t = fmaf(-wi[n], si[n], zv);
            float nr = fmaf(wr[n], sr[n], t);
            float ni = fmaf(wi[n], sr[n], wr[n] * si[n]);
            sr[n] = nr; si[n] = ni;
            acc = fmaf(cr[n], nr, acc);
            acc = fmaf(-ci[n], ni, acc);
        }
        float av = geluf(fmaf(Dv, zv, 2.f * acc));
        unsigned short hh, ll;
        split2(av, hh, ll);
        acth[ib + (size_t)j * Dm] = hh;
        actl[ib + (size_t)j * Dm] = ll;
    }
}

// ---------------- outproj GEMM (bf16x3 MFMA) + GLU ----------------
__global__ __launch_bounds__(256) void s4e_outproj(const unsigned short* __restrict__ acth,
        const unsigned short* __restrict__ actl, const unsigned short* __restrict__ wsp,
        const float* __restrict__ bias, float* __restrict__ h) {
    __shared__ unsigned short Ah[32 * 128], Al[32 * 128];
    const unsigned short* Whi = wsp;
    const unsigned short* Wlo = wsp + 32768;
    size_t l0 = (size_t)blockIdx.x * 32;
    {
        const unsigned short* gh = acth + l0 * Dm;
        const unsigned short* gl = actl + l0 * Dm;
        for (int i = threadIdx.x * 8; i < 32 * 128; i += 2048) {
            int r = i >> 7;
            int di = i ^ ((r & 7) << 3);
            *(bfrag*)&Ah[di] = *(const bfrag*)&gh[i];
            *(bfrag*)&Al[di] = *(const bfrag*)&gl[i];
        }
    }
    __syncthreads();
    int w = threadIdx.x >> 6, lane = threadIdx.x & 63;
    int col = lane & 15, q = lane >> 4;
    f32x4 acc[2][4];
#pragma unroll
    for (int m = 0; m < 2; ++m)
#pragma unroll
        for (int nt = 0; nt < 4; ++nt) acc[m][nt] = (f32x4){0.f, 0.f, 0.f, 0.f};
#pragma unroll
    for (int ks = 0; ks < 4; ++ks) {
        int kb = ks * 32 + q * 8;
        int i0 = (col * 128 + kb) ^ ((col & 7) << 3);
        int i1 = ((16 + col) * 128 + kb) ^ ((col & 7) << 3);
        bfrag a0h = *(bfrag*)&Ah[i0], a0l = *(bfrag*)&Al[i0];
        bfrag a1h = *(bfrag*)&Ah[i1], a1l = *(bfrag*)&Al[i1];
#pragma unroll
        for (int nt = 0; nt < 4; ++nt) {
            int e = (nt < 2) ? (w * 32 + nt * 16 + col) : (128 + w * 32 + (nt - 2) * 16 + col);
            bfrag bh = *(const bfrag*)&Whi[e * 128 + kb];
            bfrag bl = *(const bfrag*)&Wlo[e * 128 + kb];
            acc[0][nt] = __builtin_amdgcn_mfma_f32_16x16x32_bf16(a0h, bh, acc[0][nt], 0, 0, 0);
            acc[0][nt] = __builtin_amdgcn_mfma_f32_16x16x32_bf16(a0h, bl, acc[0][nt], 0, 0, 0);
            acc[0][nt] = __builtin_amdgcn_mfma_f32_16x16x32_bf16(a0l, bh, acc[0][nt], 0, 0, 0);
            acc[1][nt] = __builtin_amdgcn_mfma_f32_16x16x32_bf16(a1h, bh, acc[1][nt], 0, 0, 0);
            acc[1][nt] = __builtin_amdgcn_mfma_f32_16x16x32_bf16(a1h, bl, acc[1][nt], 0, 0, 0);
            acc[1][nt] = __builtin_amdgcn_mfma_f32_16x16x32_bf16(a1l, bh, acc[1][nt], 0, 0, 0);
        }
    }
#pragma unroll
    for (int m = 0; m < 2; ++m)
#pragma unroll
        for (int nt = 0; nt < 2; ++nt) {
            int dout = w * 32 + nt * 16 + col;
            float ba = bias[dout], bg = bias[dout + 128];
#pragma unroll
            for (int r = 0; r < 4; ++r) {
                int l = m * 16 + q * 4 + r;
                float a = acc[m][nt][r] + ba;
                float g = acc[m][nt + 2][r] + bg;
                float* hp = h + (l0 + l) * Dm + dout;
                *hp += a * sigmf(g);
            }
        }
}

// ---------------- fused FF GEMM (bf16x3 MFMA) ----------------
__global__ __launch_bounds__(256) void s4e_ffk(const unsigned short* __restrict__ zh,
        const unsigned short* __restrict__ zl, const unsigned short* __restrict__ wsp,
        const float* __restrict__ b1, const float* __restrict__ b2, float* __restrict__ h) {
    __shared__ unsigned short Zh[32 * 128], Zl[32 * 128];
    __shared__ unsigned short Eh[32 * 256], El[32 * 256];
    const unsigned short* W1h = wsp + 65536;
    const unsigned short* W1l = wsp + 65536 + 32768;
    const unsigned short* W2h = wsp + 131072;
    const unsigned short* W2l = wsp + 131072 + 32768;
    size_t l0 = (size_t)blockIdx.x * 32;
    {
        const unsigned short* gh = zh + l0 * Dm;
        const unsigned short* gl = zl + l0 * Dm;
        for (int i = threadIdx.x * 8; i < 32 * 128; i += 2048) {
            int r = i >> 7;
            int di = i ^ ((r & 7) << 3);
            *(bfrag*)&Zh[di] = *(const bfrag*)&gh[i];
            *(bfrag*)&Zl[di] = *(const bfrag*)&gl[i];
        }
    }
    __syncthreads();
    int w = threadIdx.x >> 6, lane = threadIdx.x & 63;
    int col = lane & 15, q = lane >> 4;
    f32x4 acc[2][4];
#pragma unroll
    for (int m = 0; m < 2; ++m)
#pragma unroll
        for (int nt = 0; nt < 4; ++nt) acc[m][nt] = (f32x4){0.f, 0.f, 0.f, 0.f};
#pragma unroll
    for (int ks = 0; ks < 4; ++ks) {
        int kb = ks * 32 + q * 8;
        int i0 = (col * 128 + kb) ^ ((col & 7) << 3);
        int i1 = ((16 + col) * 128 + kb) ^ ((col & 7) << 3);
        bfrag a0h = *(bfrag*)&Zh[i0], a0l = *(bfrag*)&Zl[i0];
        bfrag a1h = *(bfrag*)&Zh[i1], a1l = *(bfrag*)&Zl[i1];
#pragma unroll
        for (int nt = 0; nt < 4; ++nt) {
            int e = w * 64 + nt * 16 + col;
            bfrag bh = *(const bfrag*)&W1h[e * 128 + kb];
            bfrag bl = *(const bfrag*)&W1l[e * 128 + kb];
            acc[0][nt] = __builtin_amdgcn_mfma_f32_16x16x32_bf16(a0h, bh, acc[0][nt], 0, 0, 0);
            acc[0][nt] = __builtin_amdgcn_mfma_f32_16x16x32_bf16(a0h, bl, acc[0][nt], 0, 0, 0);
            acc[0][nt] = __builtin_amdgcn_mfma_f32_16x16x32_bf16(a0l, bh, acc[0][nt], 0, 0, 0);
            acc[1][nt] = __builtin_amdgcn_mfma_f32_16x16x32_bf16(a1h, bh, acc[1][nt], 0, 0, 0);
            acc[1][nt] = __builtin_amdgcn_mfma_f32_16x16x32_bf16(a1h, bl, acc[1][nt], 0, 0, 0);
            acc[1][nt] = __builtin_amdgcn_mfma_f32_16x16x32_bf16(a1l, bh, acc[1][nt], 0, 0, 0);
        }
    }
#pragma unroll
    for (int m = 0; m < 2; ++m)
#pragma unroll
        for (int nt = 0; nt < 4; ++nt) {
            int ei = w * 64 + nt * 16 + col;
            float bv = b1[ei];
#pragma unroll
            for (int r = 0; r < 4; ++r) {
                int l = m * 16 + q * 4 + r;
                float v = geluf(acc[m][nt][r] + bv);
                unsigned short hh, ll;
                split2(v, hh, ll);
                int idx = (l * 256 + ei) ^ ((l & 7) << 3);
                Eh[idx] = hh; El[idx] = ll;
            }
        }
    __syncthreads();
    f32x4 acc2[2][2];
#pragma unroll
    for (int m = 0; m < 2; ++m)
#pragma unroll
        for (int nt = 0; nt < 2; ++nt) acc2[m][nt] = (f32x4){0.f, 0.f, 0.f, 0.f};
#pragma unroll
    for (int ks = 0; ks < 8; ++ks) {
        int kb = ks * 32 + q * 8;
        int i0 = (col * 256 + kb) ^ ((col & 7) << 3);
        int i1 = ((16 + col) * 256 + kb) ^ ((col & 7) << 3);
        bfrag a0h = *(bfrag*)&Eh[i0], a0l = *(bfrag*)&El[i0];
        bfrag a1h = *(bfrag*)&Eh[i1], a1l = *(bfrag*)&El[i1];
#pragma unroll
        for (int nt = 0; nt < 2; ++nt) {
            int dout = w * 32 + nt * 16 + col;
            bfrag bh = *(const bfrag*)&W2h[dout * 256 + kb];
            bfrag bl = *(const bfrag*)&W2l[dout * 256 + kb];
            acc2[0][nt] = __builtin_amdgcn_mfma_f32_16x16x32_bf16(a0h, bh, acc2[0][nt], 0, 0, 0);
            acc2[0][nt] = __builtin_amdgcn_mfma_f32_16x16x32_bf16(a0h, bl, acc2[0][nt], 0, 0, 0);
            acc2[0][nt] = __builtin_amdgcn_mfma_f32_16x16x32_bf16(a0l, bh, acc2[0][nt], 0, 0, 0);
            acc2[1][nt] = __builtin_amdgcn_mfma_f32_16x16x32_bf16(a1h, bh, acc2[1][nt], 0, 0, 0);
            acc2[1][nt] = __builtin_amdgcn_mfma_f32_16x16x32_bf16(a1h, bl, acc2[1][nt], 0, 0, 0);
            acc2[1][nt] = __builtin_amdgcn_mfma_f32_16x16x32_bf16(a1l, bh, acc2[1][nt], 0, 0, 0);
        }
    }
#pragma unroll
    for (int m = 0; m < 2; ++m)
#pragma unroll
        for (int nt = 0; nt < 2; ++nt) {
            int dout = w * 32 + nt * 16 + col;
            float bv = b2[dout];
#pragma unroll
            for (int r = 0; r < 4; ++r) {
                int l = m * 16 + q * 4 + r;
                float* hp = h + (l0 + l) * Dm + dout;
                *hp += acc2[m][nt][r] + bv;
            }
        }
}

// ---------------- head ----------------
__global__ void s4e_head(const float* __restrict__ h, const float* __restrict__ hw,
                         const float* __restrict__ hb, int* __restrict__ out) {
    __shared__ float logit[Bb][NCl];
    int tid = threadIdx.x;
    int b = tid >> 4, c = tid & 15;
    const float* hp = h + ((size_t)b * Ls + (Ls - 1)) * Dm;
    float acc = hb[c];
    for (int d = 0; d < Dm; ++d) acc = fmaf(hp[d], hw[c * Dm + d], acc);
    logit[b][c] = acc;
    __syncthreads();
    if (c == 0) {
        float best = logit[b][0]; int bi = 0;
#pragma unroll
        for (int k = 1; k < NCl; ++k) {
            float v = logit[b][k];
            if (v > best) { best = v; bi = k; }
        }
        out[b] = bi;
    }
}

extern "C" void kernel_launch(void* const* d_in, const int* in_sizes, int n_in,
                              void* d_out, int out_size, void* d_ws, size_t ws_size,
                              hipStream_t stream) {
    const float* x        = (const float*)d_in[0];
    const float* conv_w   = (const float*)d_in[1];
    const float* conv_b   = (const float*)d_in[2];
    const float* s4_ln_w  = (const float*)d_in[3];
    const float* s4_ln_b  = (const float*)d_in[4];
    const float* s4_logdt = (const float*)d_in[5];
    const float* s4_lAr   = (const float*)d_in[6];
    const float* s4_Aim   = (const float*)d_in[7];
    const float* s4_Cre   = (const float*)d_in[8];
    const float* s4_Cim   = (const float*)d_in[9];
    const float* s4_D     = (const float*)d_in[10];
    const float* s4_ow    = (const float*)d_in[11];
    const float* s4_ob    = (const float*)d_in[12];
    const float* ff_ln_w  = (const float*)d_in[13];
    const float* ff_ln_b  = (const float*)d_in[14];
    const float* ff_w1    = (const float*)d_in[15];
    const float* ff_b1    = (const float*)d_in[16];
    const float* ff_w2    = (const float*)d_in[17];
    const float* ff_b2    = (const float*)d_in[18];
    const float* head_w   = (const float*)d_in[19];
    const float* head_b   = (const float*)d_in[20];
    int* out = (int*)d_out;

    float* ws = (float*)d_ws;
    float* h  = ws;
    float* z  = ws + 16777216;
    unsigned short* acth = (unsigned short*)(ws + 33554432);
    unsigned short* actl = (unsigned short*)(ws + 41943040);
    float2* send  = (float2*)(ws + 50331648);
    float2* sinit = (float2*)(ws + 54525952);
    float2* wv    = (float2*)(ws + 58720256);
    float2* wp    = (float2*)(ws + 58728448);
    float2* Cc    = (float2*)(ws + 58736640);
    unsigned short* wsp = (unsigned short*)(ws + 58744832);

    s4e_conv<<<BL * 32 / 256, 256, 0, stream>>>(x, conv_w, conv_b, h);
    for (int i = 0; i < NBK; ++i) {
        s4e_setup<<<1, 128, 0, stream>>>(s4_logdt + i * Dm, s4_lAr + i * Dm * Nst,
                                         s4_Aim + i * Dm * Nst, s4_Cre + i * Dm * Nst,
                                         s4_Cim + i * Dm * Nst, wv, wp, Cc);
        s4e_wsplit<<<384, 256, 0, stream>>>(s4_ow + i * Em * Dm, ff_w1 + i * Em * Dm,
                                            ff_w2 + i * Dm * Em, wsp);
        s4e_ln_f32<<<BL / 64, 256, 0, stream>>>(h, s4_ln_w + i * Dm, s4_ln_b + i * Dm, z);
        s4e_s1<<<256, 256, 0, stream>>>(z, wv, send);
        s4e_s2<<<256, 256, 0, stream>>>(wp, send, sinit);
        s4e_s3<<<256, 256, 0, stream>>>(z, wv, Cc, sinit, s4_D + i * Dm, acth, actl);
        s4e_outproj<<<BL / 32, 256, 0, stream>>>(acth, actl, wsp, s4_ob + i * Em, h);
        s4e_ln_bf<<<BL / 64, 256, 0, stream>>>(h, ff_ln_w + i * Dm, ff_ln_b + i * Dm, acth, actl);
        s4e_ffk<<<BL / 32, 256, 0, stream>>>(acth, actl, wsp, ff_b1 + i * Em, ff_b2 + i * Dm, h);
    }
    s4e_head<<<1, 256, 0, stream>>>(h, head_w, head_b, out);
}

// Round 6
// 3094.717 us; speedup vs baseline: 1.7112x; 1.0780x over previous
//
#include <hip/hip_runtime.h>
#include <math.h>

#define Bb 16
#define Ls 8192
#define Dm 128
#define NBK 6
#define Nst 32
#define NCl 16
#define Em 256
#define LC 128
#define NCH 64
#define BL (Bb*Ls)

typedef __attribute__((ext_vector_type(8))) short bfrag;   // 8 bf16 (4 VGPRs)
typedef __attribute__((ext_vector_type(4))) float f32x4;

__device__ __forceinline__ float geluf(float x) {
    float x3 = x * x * x;
    float t = tanhf(fmaf(0.0356774081f, x3, 0.7978845608f * x));
    return 0.5f * x * (1.f + t);
}
__device__ __forceinline__ float sigmf(float x) { return 1.f / (1.f + expf(-x)); }

__device__ __forceinline__ unsigned short bf16r(float x) {
    unsigned u = __float_as_uint(x);
    return (unsigned short)((u + 0x7FFFu + ((u >> 16) & 1u)) >> 16);
}
__device__ __forceinline__ void split2(float x, unsigned short& h, unsigned short& l) {
    h = bf16r(x);
    float hf = __uint_as_float(((unsigned)h) << 16);
    l = bf16r(x - hf);
}

// ---------------- conv: h[b,l,d] (token-major) ----------------
__global__ void s4e_conv(const float* __restrict__ x, const float* __restrict__ cw,
                         const float* __restrict__ cb, float* __restrict__ h) {
    int tid = blockIdx.x * 256 + threadIdx.x;     // B*L*32
    int d4 = tid & 31;
    int t = tid >> 5;
    int l = t & (Ls - 1);
    int b = t >> 13;
    const float* xb = x + (size_t)b * Ls;
    float xs[5];
#pragma unroll
    for (int k = 0; k < 5; ++k) {
        int p = l + k - 2;
        xs[k] = (p >= 0 && p < Ls) ? xb[p] : 0.f;
    }
    float4 acc;
    float* ap = &acc.x;
#pragma unroll
    for (int j = 0; j < 4; ++j) {
        int d = d4 * 4 + j;
        float a = cb[d];
#pragma unroll
        for (int k = 0; k < 5; ++k) a = fmaf(cw[d * 5 + k], xs[k], a);
        ap[j] = a;
    }
    *(float4*)&h[(size_t)t * Dm + d4 * 4] = acc;
}

// ---------------- channel LN (fp32 out): 4 lanes per token ----------------
__global__ void s4e_ln_f32(const float* __restrict__ h, const float* __restrict__ w,
                           const float* __restrict__ bb, float* __restrict__ z) {
    int tid = threadIdx.x;
    int t = blockIdx.x * 64 + (tid >> 2);
    int sub = tid & 3;
    const float* hp = h + (size_t)t * Dm + sub * 32;
    float4 v[8];
    float s = 0.f, q = 0.f;
#pragma unroll
    for (int i = 0; i < 8; ++i) {
        v[i] = *(const float4*)(hp + i * 4);
        s += v[i].x + v[i].y + v[i].z + v[i].w;
        q += v[i].x * v[i].x + v[i].y * v[i].y + v[i].z * v[i].z + v[i].w * v[i].w;
    }
    s += __shfl_xor(s, 1); s += __shfl_xor(s, 2);
    q += __shfl_xor(q, 1); q += __shfl_xor(q, 2);
    float mu = s * (1.f / Dm);
    float rs = rsqrtf(q * (1.f / Dm) - mu * mu + 1e-5f);
    float* zp = z + (size_t)t * Dm + sub * 32;
    const float* wp_ = w + sub * 32;
    const float* bp_ = bb + sub * 32;
#pragma unroll
    for (int i = 0; i < 8; ++i) {
        float4 wv4 = *(const float4*)(wp_ + i * 4);
        float4 bv4 = *(const float4*)(bp_ + i * 4);
        float4 o;
        o.x = (v[i].x - mu) * rs * wv4.x + bv4.x;
        o.y = (v[i].y - mu) * rs * wv4.y + bv4.y;
        o.z = (v[i].z - mu) * rs * wv4.z + bv4.z;
        o.w = (v[i].w - mu) * rs * wv4.w + bv4.w;
        *(float4*)(zp + i * 4) = o;
    }
}

// ---------------- S4 params: layouts [n][d], wp = w^LC ----------------
__global__ void s4e_setup(const float* __restrict__ log_dt, const float* __restrict__ lAr,
                          const float* __restrict__ Aim, const float* __restrict__ Cre,
                          const float* __restrict__ Cim, float2* __restrict__ wv,
                          float2* __restrict__ wp, float2* __restrict__ Cc) {
    int d = threadIdx.x;
    float dt = expf(log_dt[d]);
    for (int n = 0; n < Nst; ++n) {
        int id = d * Nst + n;
        float Ar = -expf(lAr[id]);
        float Ai = Aim[id];
        float xr = dt * Ar, xi = dt * Ai;
        float er = expf(xr);
        float wr = er * cosf(xi), wi = er * sinf(xi);
        wv[n * Dm + d] = make_float2(wr, wi);
        float den = Ar * Ar + Ai * Ai;
        float inv = 1.f / den;
        float fr = ((wr - 1.f) * Ar + wi * Ai) * inv;
        float fi = (wi * Ar - (wr - 1.f) * Ai) * inv;
        Cc[n * Dm + d] = make_float2(Cre[id] * fr - Cim[id] * fi, Cre[id] * fi + Cim[id] * fr);
        float pr = wr, pi = wi;
#pragma unroll
        for (int sq = 0; sq < 7; ++sq) {     // w^(2^7) = w^128 = w^LC
            float nr = pr * pr - pi * pi;
            float ni = 2.f * pr * pi;
            pr = nr; pi = ni;
        }
        wp[n * Dm + d] = make_float2(pr, pi);
    }
}

// ---------------- weight split ----------------
__global__ void s4e_wsplit(const float* __restrict__ ow, const float* __restrict__ w1,
                           const float* __restrict__ w2, unsigned short* __restrict__ base) {
    int idx = blockIdx.x * 256 + threadIdx.x;   // 98304
    int a = idx >> 15, e = idx & 32767;
    const float* src = (a == 0) ? ow : (a == 1) ? w1 : w2;
    float v = src[e];
    unsigned short hh, ll;
    split2(v, hh, ll);
    base[a * 65536 + e] = hh;
    base[a * 65536 + 32768 + e] = ll;
}

// ---------------- S1: per-chunk end states, modes split 2-way across lanes ----------------
__global__ __launch_bounds__(256) void s4e_s1(const float* __restrict__ z,
        const float2* __restrict__ wv, float2* __restrict__ send) {
    int tid = blockIdx.x * 256 + threadIdx.x;   // B*NCH*Dm*2 = 262144
    int dl = tid & 31;
    int m  = (tid >> 5) & 1;
    int dh = (tid >> 6) & 3;
    int c  = (tid >> 8) & (NCH - 1);
    int b  = tid >> 14;
    int d  = dh * 32 + dl;
    int n0 = m * 16;
    float wr[16], wi[16], sr[16], si[16];
#pragma unroll
    for (int k = 0; k < 16; ++k) {
        float2 t = wv[(n0 + k) * Dm + d];
        wr[k] = t.x; wi[k] = t.y; sr[k] = 0.f; si[k] = 0.f;
    }
    const float* zp = z + ((size_t)b * Ls + c * LC) * Dm + d;
#pragma unroll 4
    for (int j = 0; j < LC; ++j) {
        float zv = zp[(size_t)j * Dm];
#pragma unroll
        for (int k = 0; k < 16; ++k) {
            float t = fmaf(-wi[k], si[k], zv);
            float nr = fmaf(wr[k], sr[k], t);
            float ni = fmaf(wi[k], sr[k], wr[k] * si[k]);
            sr[k] = nr; si[k] = ni;
        }
    }
    float2* o = send + ((size_t)(b * NCH + c) * Nst + n0) * Dm + d;
#pragma unroll
    for (int k = 0; k < 16; ++k) o[k * Dm] = make_float2(sr[k], si[k]);
}

// ---------------- S2: in-place cross-chunk prefix ----------------
__global__ void s4e_s2(const float2* __restrict__ wp, float2* __restrict__ s) {
    int tid = blockIdx.x * 256 + threadIdx.x;   // B*Nst*Dm = 65536
    int d = tid & 127;
    int n = (tid >> 7) & 31;
    int b = tid >> 12;
    float2 W = wp[n * Dm + d];
    float Sr = 0.f, Si = 0.f;
    size_t base = ((size_t)(b * NCH) * Nst + n) * Dm + d;
    size_t cs = (size_t)Nst * Dm;
    for (int c0 = 0; c0 < NCH; c0 += 8) {
        float2 E[8];
#pragma unroll
        for (int k = 0; k < 8; ++k) E[k] = s[base + (size_t)(c0 + k) * cs];
#pragma unroll
        for (int k = 0; k < 8; ++k) {
            float2 o = make_float2(Sr, Si);
            float nr = fmaf(W.x, Sr, fmaf(-W.y, Si, E[k].x));
            float ni = fmaf(W.x, Si, fmaf(W.y, Sr, E[k].y));
            Sr = nr; Si = ni;
            s[base + (size_t)(c0 + k) * cs] = o;
        }
    }
}

// ---------------- S3: re-scan + gelu(y + Dsk*z) -> act bf16 hi/lo (modes 2-way) ----------------
__global__ __launch_bounds__(256) void s4e_s3(const float* __restrict__ z,
        const float2* __restrict__ wv, const float2* __restrict__ Cc,
        const float2* __restrict__ sinit, const float* __restrict__ Dsk,
        unsigned short* __restrict__ acth, unsigned short* __restrict__ actl) {
    int tid = blockIdx.x * 256 + threadIdx.x;
    int dl = tid & 31;
    int m  = (tid >> 5) & 1;
    int dh = (tid >> 6) & 3;
    int c  = (tid >> 8) & (NCH - 1);
    int b  = tid >> 14;
    int d  = dh * 32 + dl;
    int n0 = m * 16;
    float wr[16], wi[16], cr[16], ci[16], sr[16], si[16];
    const float2* s0 = sinit + ((size_t)(b * NCH + c) * Nst + n0) * Dm + d;
#pragma unroll
    for (int k = 0; k < 16; ++k) {
        float2 t = wv[(n0 + k) * Dm + d];  wr[k] = t.x; wi[k] = t.y;
        float2 cc = Cc[(n0 + k) * Dm + d]; cr[k] = cc.x; ci[k] = cc.y;
        float2 ss = s0[k * Dm];            sr[k] = ss.x; si[k] = ss.y;
    }
    float Dv = Dsk[d];
    size_t ib = ((size_t)b * Ls + c * LC) * Dm + d;
#pragma unroll 2
    for (int j = 0; j < LC; ++j) {
        float zv = z[ib + (size_t)j * Dm];
        float acc = 0.f;
#pragma unroll
        for (int k = 0; k < 16; ++k) {
            float t = fmaf(-wi[k], si[k], zv);
            float nr = fmaf(wr[k], sr[k], t);
            float ni = fmaf(wi[k], sr[k], wr[k] * si[k]);
            sr[k] = nr; si[k] = ni;
            acc = fmaf(cr[k], nr, acc);
            acc = fmaf(-ci[k], ni, acc);
        }
        acc += __shfl_xor(acc, 32);
        float av = geluf(fmaf(Dv, zv, 2.f * acc));
        unsigned short hh, ll;
        split2(av, hh, ll);
        if (m == 0) {
            acth[ib + (size_t)j * Dm] = hh;
            actl[ib + (size_t)j * Dm] = ll;
        }
    }
}

// ---------------- outproj GEMM (bf16x3 MFMA) + GLU, LDS-bounced epilogue ----------------
__global__ __launch_bounds__(256) void s4e_outproj(const unsigned short* __restrict__ acth,
        const unsigned short* __restrict__ actl, const unsigned short* __restrict__ wsp,
        const float* __restrict__ bias, float* __restrict__ h) {
    __shared__ __align__(16) unsigned short smem[8192];   // Ah 8K | Al 8K ; Rf aliases all 16K
    unsigned short* Ah = smem;
    unsigned short* Al = smem + 4096;
    float* Rf = (float*)smem;
    const unsigned short* Whi = wsp;
    const unsigned short* Wlo = wsp + 32768;
    size_t l0 = (size_t)blockIdx.x * 32;
    int tid = threadIdx.x;
    {
        const unsigned short* gh = acth + l0 * Dm;
        const unsigned short* gl = actl + l0 * Dm;
        for (int i = tid * 8; i < 32 * 128; i += 2048) {
            int r = i >> 7;
            int di = i ^ ((r & 7) << 3);
            *(bfrag*)&Ah[di] = *(const bfrag*)&gh[i];
            *(bfrag*)&Al[di] = *(const bfrag*)&gl[i];
        }
    }
    __syncthreads();
    int w = tid >> 6, lane = tid & 63;
    int col = lane & 15, q = lane >> 4;
    f32x4 acc[2][4];
#pragma unroll
    for (int m = 0; m < 2; ++m)
#pragma unroll
        for (int nt = 0; nt < 4; ++nt) acc[m][nt] = (f32x4){0.f, 0.f, 0.f, 0.f};
#pragma unroll
    for (int ks = 0; ks < 4; ++ks) {
        int kb = ks * 32 + q * 8;
        int i0 = (col * 128 + kb) ^ ((col & 7) << 3);
        int i1 = ((16 + col) * 128 + kb) ^ ((col & 7) << 3);
        bfrag a0h = *(bfrag*)&Ah[i0], a0l = *(bfrag*)&Al[i0];
        bfrag a1h = *(bfrag*)&Ah[i1], a1l = *(bfrag*)&Al[i1];
#pragma unroll
        for (int nt = 0; nt < 4; ++nt) {
            int e = (nt < 2) ? (w * 32 + nt * 16 + col) : (128 + w * 32 + (nt - 2) * 16 + col);
            bfrag bh = *(const bfrag*)&Whi[e * 128 + kb];
            bfrag bl = *(const bfrag*)&Wlo[e * 128 + kb];
            acc[0][nt] = __builtin_amdgcn_mfma_f32_16x16x32_bf16(a0h, bh, acc[0][nt], 0, 0, 0);
            acc[0][nt] = __builtin_amdgcn_mfma_f32_16x16x32_bf16(a0h, bl, acc[0][nt], 0, 0, 0);
            acc[0][nt] = __builtin_amdgcn_mfma_f32_16x16x32_bf16(a0l, bh, acc[0][nt], 0, 0, 0);
            acc[1][nt] = __builtin_amdgcn_mfma_f32_16x16x32_bf16(a1h, bh, acc[1][nt], 0, 0, 0);
            acc[1][nt] = __builtin_amdgcn_mfma_f32_16x16x32_bf16(a1h, bl, acc[1][nt], 0, 0, 0);
            acc[1][nt] = __builtin_amdgcn_mfma_f32_16x16x32_bf16(a1l, bh, acc[1][nt], 0, 0, 0);
        }
    }
    __syncthreads();   // all Ah/Al reads done before Rf overwrite
#pragma unroll
    for (int m = 0; m < 2; ++m)
#pragma unroll
        for (int nt = 0; nt < 2; ++nt) {
            int dout = w * 32 + nt * 16 + col;
            float ba = bias[dout], bg = bias[dout + 128];
#pragma unroll
            for (int r = 0; r < 4; ++r) {
                int l = m * 16 + q * 4 + r;
                float a = acc[m][nt][r] + ba;
                float g = acc[m][nt + 2][r] + bg;
                Rf[l * 128 + dout] = a * sigmf(g);
            }
        }
    __syncthreads();
    size_t gb = l0 * Dm + (size_t)tid * 16;
#pragma unroll
    for (int i = 0; i < 4; ++i) {
        float4 r = *(float4*)&Rf[tid * 16 + i * 4];
        float4 hv = *(float4*)&h[gb + i * 4];
        hv.x += r.x; hv.y += r.y; hv.z += r.z; hv.w += r.w;
        *(float4*)&h[gb + i * 4] = hv;
    }
}

// ---------------- fused LN + FF GEMM (bf16x3 MFMA), LDS-bounced epilogue ----------------
__global__ __launch_bounds__(256) void s4e_ffk(const float* __restrict__ lnw,
        const float* __restrict__ lnb, const unsigned short* __restrict__ wsp,
        const float* __restrict__ b1, const float* __restrict__ b2, float* __restrict__ h) {
    __shared__ __align__(16) unsigned short smem[24576]; // Zh 8K|Zl 8K|Eh 16K|El 16K (bytes)
    unsigned short* Zh = smem;
    unsigned short* Zl = smem + 4096;
    unsigned short* Eh = smem + 8192;
    unsigned short* El = smem + 16384;
    float* Rf = (float*)smem;                 // aliases Zh+Zl (16 KB)
    const unsigned short* W1h = wsp + 65536;
    const unsigned short* W1l = wsp + 65536 + 32768;
    const unsigned short* W2h = wsp + 131072;
    const unsigned short* W2l = wsp + 131072 + 32768;
    size_t l0 = (size_t)blockIdx.x * 32;
    int tid = threadIdx.x;
    // ---- fused LN: thread covers elements [tid*16, tid*16+16) of the 32x128 tile
    float hf[16];
    float s = 0.f, qq = 0.f;
    {
        const float* hp = h + l0 * Dm + (size_t)tid * 16;
#pragma unroll
        for (int i = 0; i < 4; ++i) {
            float4 v = *(const float4*)(hp + i * 4);
            hf[i * 4 + 0] = v.x; hf[i * 4 + 1] = v.y;
            hf[i * 4 + 2] = v.z; hf[i * 4 + 3] = v.w;
            s += v.x + v.y + v.z + v.w;
            qq += v.x * v.x + v.y * v.y + v.z * v.z + v.w * v.w;
        }
    }
    s  += __shfl_xor(s, 1);  s += __shfl_xor(s, 2);  s += __shfl_xor(s, 4);
    qq += __shfl_xor(qq, 1); qq += __shfl_xor(qq, 2); qq += __shfl_xor(qq, 4);
    float mu = s * (1.f / Dm);
    float rs = rsqrtf(qq * (1.f / Dm) - mu * mu + 1e-5f);
    int tok = tid >> 3, dc = (tid & 7) * 16;
#pragma unroll
    for (int g = 0; g < 2; ++g) {
        bfrag vh, vl;
#pragma unroll
        for (int k = 0; k < 8; ++k) {
            int d = dc + g * 8 + k;
            float v = (hf[g * 8 + k] - mu) * rs * lnw[d] + lnb[d];
            unsigned short hh, ll;
            split2(v, hh, ll);
            vh[k] = (short)hh; vl[k] = (short)ll;
        }
        int idx = (tok * 128 + dc + g * 8) ^ ((tok & 7) << 3);
        *(bfrag*)&Zh[idx] = vh;
        *(bfrag*)&Zl[idx] = vl;
    }
    __syncthreads();
    int w = tid >> 6, lane = tid & 63;
    int col = lane & 15, q = lane >> 4;
    f32x4 acc[2][4];
#pragma unroll
    for (int m = 0; m < 2; ++m)
#pragma unroll
        for (int nt = 0; nt < 4; ++nt) acc[m][nt] = (f32x4){0.f, 0.f, 0.f, 0.f};
#pragma unroll
    for (int ks = 0; ks < 4; ++ks) {
        int kb = ks * 32 + q * 8;
        int i0 = (col * 128 + kb) ^ ((col & 7) << 3);
        int i1 = ((16 + col) * 128 + kb) ^ ((col & 7) << 3);
        bfrag a0h = *(bfrag*)&Zh[i0], a0l = *(bfrag*)&Zl[i0];
        bfrag a1h = *(bfrag*)&Zh[i1], a1l = *(bfrag*)&Zl[i1];
#pragma unroll
        for (int nt = 0; nt < 4; ++nt) {
            int e = w * 64 + nt * 16 + col;
            bfrag bh = *(const bfrag*)&W1h[e * 128 + kb];
            bfrag bl = *(const bfrag*)&W1l[e * 128 + kb];
            acc[0][nt] = __builtin_amdgcn_mfma_f32_16x16x32_bf16(a0h, bh, acc[0][nt], 0, 0, 0);
            acc[0][nt] = __builtin_amdgcn_mfma_f32_16x16x32_bf16(a0h, bl, acc[0][nt], 0, 0, 0);
            acc[0][nt] = __builtin_amdgcn_mfma_f32_16x16x32_bf16(a0l, bh, acc[0][nt], 0, 0, 0);
            acc[1][nt] = __builtin_amdgcn_mfma_f32_16x16x32_bf16(a1h, bh, acc[1][nt], 0, 0, 0);
            acc[1][nt] = __builtin_amdgcn_mfma_f32_16x16x32_bf16(a1h, bl, acc[1][nt], 0, 0, 0);
            acc[1][nt] = __builtin_amdgcn_mfma_f32_16x16x32_bf16(a1l, bh, acc[1][nt], 0, 0, 0);
        }
    }
    // ff1 epilogue -> E (separate LDS region; no conflict with Z reads)
#pragma unroll
    for (int m = 0; m < 2; ++m)
#pragma unroll
        for (int nt = 0; nt < 4; ++nt) {
            int ei = w * 64 + nt * 16 + col;
            float bv = b1[ei];
#pragma unroll
            for (int r = 0; r < 4; ++r) {
                int l = m * 16 + q * 4 + r;
                float v = geluf(acc[m][nt][r] + bv);
                unsigned short hh, ll;
                split2(v, hh, ll);
                int idx = (l * 256 + ei) ^ ((l & 7) << 3);
                Eh[idx] = hh; El[idx] = ll;
            }
        }
    __syncthreads();   // E complete; Z dead from here on
    f32x4 acc2[2][2];
#pragma unroll
    for (int m = 0; m < 2; ++m)
#pragma unroll
        for (int nt = 0; nt < 2; ++nt) acc2[m][nt] = (f32x4){0.f, 0.f, 0.f, 0.f};
#pragma unroll
    for (int ks = 0; ks < 8; ++ks) {
        int kb = ks * 32 + q * 8;
        int i0 = (col * 256 + kb) ^ ((col & 7) << 3);
        int i1 = ((16 + col) * 256 + kb) ^ ((col & 7) << 3);
        bfrag a0h = *(bfrag*)&Eh[i0], a0l = *(bfrag*)&El[i0];
        bfrag a1h = *(bfrag*)&Eh[i1], a1l = *(bfrag*)&El[i1];
#pragma unroll
        for (int nt = 0; nt < 2; ++nt) {
            int dout = w * 32 + nt * 16 + col;
            bfrag bh = *(const bfrag*)&W2h[dout * 256 + kb];
            bfrag bl = *(const bfrag*)&W2l[dout * 256 + kb];
            acc2[0][nt] = __builtin_amdgcn_mfma_f32_16x16x32_bf16(a0h, bh, acc2[0][nt], 0, 0, 0);
            acc2[0][nt] = __builtin_amdgcn_mfma_f32_16x16x32_bf16(a0h, bl, acc2[0][nt], 0, 0, 0);
            acc2[0][nt] = __builtin_amdgcn_mfma_f32_16x16x32_bf16(a0l, bh, acc2[0][nt], 0, 0, 0);
            acc2[1][nt] = __builtin_amdgcn_mfma_f32_16x16x32_bf16(a1h, bh, acc2[1][nt], 0, 0, 0);
            acc2[1][nt] = __builtin_amdgcn_mfma_f32_16x16x32_bf16(a1h, bl, acc2[1][nt], 0, 0, 0);
            acc2[1][nt] = __builtin_amdgcn_mfma_f32_16x16x32_bf16(a1l, bh, acc2[1][nt], 0, 0, 0);
        }
    }
    // Rf writes overwrite Z region (dead after the barrier above)
#pragma unroll
    for (int m = 0; m < 2; ++m)
#pragma unroll
        for (int nt = 0; nt < 2; ++nt) {
            int dout = w * 32 + nt * 16 + col;
            float bv = b2[dout];
#pragma unroll
            for (int r = 0; r < 4; ++r) {
                int l = m * 16 + q * 4 + r;
                Rf[l * 128 + dout] = acc2[m][nt][r] + bv;
            }
        }
    __syncthreads();
    size_t gb = l0 * Dm + (size_t)tid * 16;
#pragma unroll
    for (int i = 0; i < 4; ++i) {
        float4 r = *(float4*)&Rf[tid * 16 + i * 4];
        float4 o;
        o.x = hf[i * 4 + 0] + r.x; o.y = hf[i * 4 + 1] + r.y;
        o.z = hf[i * 4 + 2] + r.z; o.w = hf[i * 4 + 3] + r.w;
        *(float4*)&h[gb + i * 4] = o;
    }
}

// ---------------- head ----------------
__global__ void s4e_head(const float* __restrict__ h, const float* __restrict__ hw,
                         const float* __restrict__ hb, int* __restrict__ out) {
    __shared__ float logit[Bb][NCl];
    int tid = threadIdx.x;
    int b = tid >> 4, c = tid & 15;
    const float* hp = h + ((size_t)b * Ls + (Ls - 1)) * Dm;
    float acc = hb[c];
    for (int d = 0; d < Dm; ++d) acc = fmaf(hp[d], hw[c * Dm + d], acc);
    logit[b][c] = acc;
    __syncthreads();
    if (c == 0) {
        float best = logit[b][0]; int bi = 0;
#pragma unroll
        for (int k = 1; k < NCl; ++k) {
            float v = logit[b][k];
            if (v > best) { best = v; bi = k; }
        }
        out[b] = bi;
    }
}

extern "C" void kernel_launch(void* const* d_in, const int* in_sizes, int n_in,
                              void* d_out, int out_size, void* d_ws, size_t ws_size,
                              hipStream_t stream) {
    const float* x        = (const float*)d_in[0];
    const float* conv_w   = (const float*)d_in[1];
    const float* conv_b   = (const float*)d_in[2];
    const float* s4_ln_w  = (const float*)d_in[3];
    const float* s4_ln_b  = (const float*)d_in[4];
    const float* s4_logdt = (const float*)d_in[5];
    const float* s4_lAr   = (const float*)d_in[6];
    const float* s4_Aim   = (const float*)d_in[7];
    const float* s4_Cre   = (const float*)d_in[8];
    const float* s4_Cim   = (const float*)d_in[9];
    const float* s4_D     = (const float*)d_in[10];
    const float* s4_ow    = (const float*)d_in[11];
    const float* s4_ob    = (const float*)d_in[12];
    const float* ff_ln_w  = (const float*)d_in[13];
    const float* ff_ln_b  = (const float*)d_in[14];
    const float* ff_w1    = (const float*)d_in[15];
    const float* ff_b1    = (const float*)d_in[16];
    const float* ff_w2    = (const float*)d_in[17];
    const float* ff_b2    = (const float*)d_in[18];
    const float* head_w   = (const float*)d_in[19];
    const float* head_b   = (const float*)d_in[20];
    int* out = (int*)d_out;

    float* ws = (float*)d_ws;
    float* h  = ws;                                        // 64 MB
    float* z  = ws + 16777216;                             // 64 MB
    unsigned short* acth = (unsigned short*)(ws + 33554432);  // 32 MB
    unsigned short* actl = (unsigned short*)(ws + 41943040);  // 32 MB
    float2* send  = (float2*)(ws + 50331648);              // 33.5 MB (in-place prefix)
    float2* wv    = (float2*)(ws + 58720256);
    float2* wp    = (float2*)(ws + 58728448);
    float2* Cc    = (float2*)(ws + 58736640);
    unsigned short* wsp = (unsigned short*)(ws + 58744832);

    s4e_conv<<<BL * 32 / 256, 256, 0, stream>>>(x, conv_w, conv_b, h);
    for (int i = 0; i < NBK; ++i) {
        s4e_setup<<<1, 128, 0, stream>>>(s4_logdt + i * Dm, s4_lAr + i * Dm * Nst,
                                         s4_Aim + i * Dm * Nst, s4_Cre + i * Dm * Nst,
                                         s4_Cim + i * Dm * Nst, wv, wp, Cc);
        s4e_wsplit<<<384, 256, 0, stream>>>(s4_ow + i * Em * Dm, ff_w1 + i * Em * Dm,
                                            ff_w2 + i * Dm * Em, wsp);
        s4e_ln_f32<<<BL / 64, 256, 0, stream>>>(h, s4_ln_w + i * Dm, s4_ln_b + i * Dm, z);
        s4e_s1<<<1024, 256, 0, stream>>>(z, wv, send);
        s4e_s2<<<256, 256, 0, stream>>>(wp, send);
        s4e_s3<<<1024, 256, 0, stream>>>(z, wv, Cc, send, s4_D + i * Dm, acth, actl);
        s4e_outproj<<<BL / 32, 256, 0, stream>>>(acth, actl, wsp, s4_ob + i * Em, h);
        s4e_ffk<<<BL / 32, 256, 0, stream>>>(ff_ln_w + i * Dm, ff_ln_b + i * Dm, wsp,
                                             ff_b1 + i * Em, ff_b2 + i * Dm, h);
    }
    s4e_head<<<1, 256, 0, stream>>>(h, head_w, head_b, out);
}

// Round 8
// 2422.124 us; speedup vs baseline: 2.1863x; 1.2777x over previous
//
#include <hip/hip_runtime.h>
#include <math.h>

#define Bb 16
#define Ls 8192
#define Dm 128
#define NBK 6
#define Nst 32
#define NCl 16
#define Em 256
#define LC 128
#define NCH 64
#define BL (Bb*Ls)

typedef __attribute__((ext_vector_type(8))) short bfrag;   // 8 bf16 (4 VGPRs)
typedef __attribute__((ext_vector_type(4))) float f32x4;

__device__ __forceinline__ float geluf(float x) {
    float x3 = x * x * x;
    float t = tanhf(fmaf(0.0356774081f, x3, 0.7978845608f * x));
    return 0.5f * x * (1.f + t);
}
__device__ __forceinline__ float sigmf(float x) { return 1.f / (1.f + expf(-x)); }

__device__ __forceinline__ unsigned short bf16r(float x) {
    unsigned u = __float_as_uint(x);
    return (unsigned short)((u + 0x7FFFu + ((u >> 16) & 1u)) >> 16);
}
__device__ __forceinline__ void split2(float x, unsigned short& h, unsigned short& l) {
    h = bf16r(x);
    float hf = __uint_as_float(((unsigned)h) << 16);
    l = bf16r(x - hf);
}

// ---------------- conv: h[b,l,d] (token-major) ----------------
__global__ void s4e_conv(const float* __restrict__ x, const float* __restrict__ cw,
                         const float* __restrict__ cb, float* __restrict__ h) {
    int tid = blockIdx.x * 256 + threadIdx.x;     // B*L*32
    int d4 = tid & 31;
    int t = tid >> 5;
    int l = t & (Ls - 1);
    int b = t >> 13;
    const float* xb = x + (size_t)b * Ls;
    float xs[5];
#pragma unroll
    for (int k = 0; k < 5; ++k) {
        int p = l + k - 2;
        xs[k] = (p >= 0 && p < Ls) ? xb[p] : 0.f;
    }
    float4 acc;
    float* ap = &acc.x;
#pragma unroll
    for (int j = 0; j < 4; ++j) {
        int d = d4 * 4 + j;
        float a = cb[d];
#pragma unroll
        for (int k = 0; k < 5; ++k) a = fmaf(cw[d * 5 + k], xs[k], a);
        ap[j] = a;
    }
    *(float4*)&h[(size_t)t * Dm + d4 * 4] = acc;
}

// ---------------- LN stats: per-token mu, rs ----------------
__global__ void s4e_lnstat(const float* __restrict__ h, float2* __restrict__ stats) {
    int tid = threadIdx.x;
    int t = blockIdx.x * 64 + (tid >> 2);
    int sub = tid & 3;
    const float* hp = h + (size_t)t * Dm + sub * 32;
    float s = 0.f, q = 0.f;
#pragma unroll
    for (int i = 0; i < 8; ++i) {
        float4 v = *(const float4*)(hp + i * 4);
        s += v.x + v.y + v.z + v.w;
        q += v.x * v.x + v.y * v.y + v.z * v.z + v.w * v.w;
    }
    s += __shfl_xor(s, 1); s += __shfl_xor(s, 2);
    q += __shfl_xor(q, 1); q += __shfl_xor(q, 2);
    float mu = s * (1.f / Dm);
    float rs = rsqrtf(q * (1.f / Dm) - mu * mu + 1e-5f);
    if (sub == 0) stats[t] = make_float2(mu, rs);
}

// ---------------- S4 params: layouts [n][d], wp = w^LC ----------------
__global__ void s4e_setup(const float* __restrict__ log_dt, const float* __restrict__ lAr,
                          const float* __restrict__ Aim, const float* __restrict__ Cre,
                          const float* __restrict__ Cim, float2* __restrict__ wv,
                          float2* __restrict__ wp, float2* __restrict__ Cc) {
    int d = threadIdx.x;
    float dt = expf(log_dt[d]);
    for (int n = 0; n < Nst; ++n) {
        int id = d * Nst + n;
        float Ar = -expf(lAr[id]);
        float Ai = Aim[id];
        float xr = dt * Ar, xi = dt * Ai;
        float er = expf(xr);
        float wr = er * cosf(xi), wi = er * sinf(xi);
        wv[n * Dm + d] = make_float2(wr, wi);
        float den = Ar * Ar + Ai * Ai;
        float inv = 1.f / den;
        float fr = ((wr - 1.f) * Ar + wi * Ai) * inv;
        float fi = (wi * Ar - (wr - 1.f) * Ai) * inv;
        Cc[n * Dm + d] = make_float2(Cre[id] * fr - Cim[id] * fi, Cre[id] * fi + Cim[id] * fr);
        float pr = wr, pi = wi;
#pragma unroll
        for (int sq = 0; sq < 7; ++sq) {     // w^(2^7) = w^128 = w^LC
            float nr = pr * pr - pi * pi;
            float ni = 2.f * pr * pi;
            pr = nr; pi = ni;
        }
        wp[n * Dm + d] = make_float2(pr, pi);
    }
}

// ---------------- weight split + MFMA-fragment-order pack ----------------
// packed[((rt*KT + kt)*64 + lane)*8 + j] = W[rt*16 + (lane&15)][kt*32 + (lane>>4)*8 + j]
__global__ void s4e_wsplit(const float* __restrict__ ow, const float* __restrict__ w1,
                           const float* __restrict__ w2, unsigned short* __restrict__ base) {
    int idx = blockIdx.x * 256 + threadIdx.x;   // 12288 groups of 8
    int mat = idx >> 12;
    int g = idx & 4095;
    int lane = g & 63;
    int fid = g >> 6;
    int col = lane & 15, q = lane >> 4;
    const float* src;
    unsigned short *dh, *dl_;
    int rt, kt, K;
    if (mat == 0)      { src = ow; K = 128; dh = base;          dl_ = base + 32768;  rt = fid >> 2; kt = fid & 3; }
    else if (mat == 1) { src = w1; K = 128; dh = base + 65536;  dl_ = base + 98304;  rt = fid >> 2; kt = fid & 3; }
    else               { src = w2; K = 256; dh = base + 131072; dl_ = base + 163840; rt = fid >> 3; kt = fid & 7; }
    int row = rt * 16 + col;
    int k0 = kt * 32 + q * 8;
    const float* sp = src + row * K + k0;
    bfrag vh, vl;
#pragma unroll
    for (int j = 0; j < 8; ++j) {
        unsigned short hh, ll;
        split2(sp[j], hh, ll);
        vh[j] = (short)hh; vl[j] = (short)ll;
    }
    *(bfrag*)&dh[g * 8] = vh;
    *(bfrag*)&dl_[g * 8] = vl;
}

// ---------------- S1: per-chunk end states, inline LN, modes 2-way ----------------
__global__ __launch_bounds__(256) void s4e_s1(const float* __restrict__ h,
        const float2* __restrict__ stats, const float* __restrict__ lnw,
        const float* __restrict__ lnb, const float2* __restrict__ wv,
        float2* __restrict__ send) {
    int tid = blockIdx.x * 256 + threadIdx.x;   // B*NCH*Dm*2 = 262144
    int dl = tid & 31;
    int m  = (tid >> 5) & 1;
    int dh = (tid >> 6) & 3;
    int c  = (tid >> 8) & (NCH - 1);
    int b  = tid >> 14;
    int d  = dh * 32 + dl;
    int n0 = m * 16;
    float wr[16], wi[16], sr[16], si[16];
#pragma unroll
    for (int k = 0; k < 16; ++k) {
        float2 t = wv[(n0 + k) * Dm + d];
        wr[k] = t.x; wi[k] = t.y; sr[k] = 0.f; si[k] = 0.f;
    }
    float wd = lnw[d], bd = lnb[d];
    const float* hp = h + ((size_t)b * Ls + c * LC) * Dm + d;
    const float2* st = stats + (size_t)b * Ls + c * LC;
#pragma unroll 4
    for (int j = 0; j < LC; ++j) {
        float2 sj = st[j];
        float zv = (hp[(size_t)j * Dm] - sj.x) * sj.y * wd + bd;
#pragma unroll
        for (int k = 0; k < 16; ++k) {
            float t = fmaf(-wi[k], si[k], zv);
            float nr = fmaf(wr[k], sr[k], t);
            float ni = fmaf(wi[k], sr[k], wr[k] * si[k]);
            sr[k] = nr; si[k] = ni;
        }
    }
    float2* o = send + ((size_t)(b * NCH + c) * Nst + n0) * Dm + d;
#pragma unroll
    for (int k = 0; k < 16; ++k) o[k * Dm] = make_float2(sr[k], si[k]);
}

// ---------------- S2: in-place cross-chunk prefix ----------------
__global__ void s4e_s2(const float2* __restrict__ wp, float2* __restrict__ s) {
    int tid = blockIdx.x * 256 + threadIdx.x;   // B*Nst*Dm = 65536
    int d = tid & 127;
    int n = (tid >> 7) & 31;
    int b = tid >> 12;
    float2 W = wp[n * Dm + d];
    float Sr = 0.f, Si = 0.f;
    size_t base = ((size_t)(b * NCH) * Nst + n) * Dm + d;
    size_t cs = (size_t)Nst * Dm;
    for (int c0 = 0; c0 < NCH; c0 += 8) {
        float2 E[8];
#pragma unroll
        for (int k = 0; k < 8; ++k) E[k] = s[base + (size_t)(c0 + k) * cs];
#pragma unroll
        for (int k = 0; k < 8; ++k) {
            float2 o = make_float2(Sr, Si);
            float nr = fmaf(W.x, Sr, fmaf(-W.y, Si, E[k].x));
            float ni = fmaf(W.x, Si, fmaf(W.y, Sr, E[k].y));
            Sr = nr; Si = ni;
            s[base + (size_t)(c0 + k) * cs] = o;
        }
    }
}

// ---------------- S3: re-scan, inline LN, gelu(y + Dsk*z) -> act bf16 hi/lo ----------------
__global__ __launch_bounds__(256) void s4e_s3(const float* __restrict__ h,
        const float2* __restrict__ stats, const float* __restrict__ lnw,
        const float* __restrict__ lnb, const float2* __restrict__ wv,
        const float2* __restrict__ Cc, const float2* __restrict__ sinit,
        const float* __restrict__ Dsk,
        unsigned short* __restrict__ acth, unsigned short* __restrict__ actl) {
    int tid = blockIdx.x * 256 + threadIdx.x;
    int dl = tid & 31;
    int m  = (tid >> 5) & 1;
    int dh = (tid >> 6) & 3;
    int c  = (tid >> 8) & (NCH - 1);
    int b  = tid >> 14;
    int d  = dh * 32 + dl;
    int n0 = m * 16;
    float wr[16], wi[16], cr[16], ci[16], sr[16], si[16];
    const float2* s0 = sinit + ((size_t)(b * NCH + c) * Nst + n0) * Dm + d;
#pragma unroll
    for (int k = 0; k < 16; ++k) {
        float2 t = wv[(n0 + k) * Dm + d];  wr[k] = t.x; wi[k] = t.y;
        float2 cc = Cc[(n0 + k) * Dm + d]; cr[k] = cc.x; ci[k] = cc.y;
        float2 ss = s0[k * Dm];            sr[k] = ss.x; si[k] = ss.y;
    }
    float wd = lnw[d], bd = lnb[d];
    float Dv = Dsk[d];
    size_t ib = ((size_t)b * Ls + c * LC) * Dm + d;
    const float2* st = stats + (size_t)b * Ls + c * LC;
#pragma unroll 2
    for (int j = 0; j < LC; ++j) {
        float2 sj = st[j];
        float zv = (h[ib + (size_t)j * Dm] - sj.x) * sj.y * wd + bd;
        float acc = 0.f;
#pragma unroll
        for (int k = 0; k < 16; ++k) {
            float t = fmaf(-wi[k], si[k], zv);
            float nr = fmaf(wr[k], sr[k], t);
            float ni = fmaf(wi[k], sr[k], wr[k] * si[k]);
            sr[k] = nr; si[k] = ni;
            acc = fmaf(cr[k], nr, acc);
            acc = fmaf(-ci[k], ni, acc);
        }
        acc += __shfl_xor(acc, 32);
        float av = geluf(fmaf(Dv, zv, 2.f * acc));
        unsigned short hh, ll;
        split2(av, hh, ll);
        if (m == 0) {
            acth[ib + (size_t)j * Dm] = hh;
            actl[ib + (size_t)j * Dm] = ll;
        }
    }
}

// ---------------- outproj GEMM (bf16x3 MFMA, packed weights) + GLU ----------------
__global__ __launch_bounds__(256) void s4e_outproj(const unsigned short* __restrict__ acth,
        const unsigned short* __restrict__ actl, const unsigned short* __restrict__ wsp,
        const float* __restrict__ bias, float* __restrict__ h) {
    __shared__ __align__(16) unsigned short smem[8192];   // Ah 8K | Al 8K ; Rf aliases 16K
    unsigned short* Ah = smem;
    unsigned short* Al = smem + 4096;
    float* Rf = (float*)smem;
    const unsigned short* Whi = wsp;
    const unsigned short* Wlo = wsp + 32768;
    size_t l0 = (size_t)blockIdx.x * 32;
    int tid = threadIdx.x;
    {
        const unsigned short* gh = acth + l0 * Dm;
        const unsigned short* gl = actl + l0 * Dm;
        for (int i = tid * 8; i < 32 * 128; i += 2048) {
            int r = i >> 7;
            int di = i ^ ((r & 7) << 3);
            *(bfrag*)&Ah[di] = *(const bfrag*)&gh[i];
            *(bfrag*)&Al[di] = *(const bfrag*)&gl[i];
        }
    }
    __syncthreads();
    int w = tid >> 6, lane = tid & 63;
    int col = lane & 15, q = lane >> 4;
    f32x4 acc[2][4];
#pragma unroll
    for (int m = 0; m < 2; ++m)
#pragma unroll
        for (int nt = 0; nt < 4; ++nt) acc[m][nt] = (f32x4){0.f, 0.f, 0.f, 0.f};
#pragma unroll
    for (int ks = 0; ks < 4; ++ks) {
        int kb = ks * 32 + q * 8;
        int i0 = (col * 128 + kb) ^ ((col & 7) << 3);
        int i1 = ((16 + col) * 128 + kb) ^ ((col & 7) << 3);
        bfrag a0h = *(bfrag*)&Ah[i0], a0l = *(bfrag*)&Al[i0];
        bfrag a1h = *(bfrag*)&Ah[i1], a1l = *(bfrag*)&Al[i1];
#pragma unroll
        for (int nt = 0; nt < 4; ++nt) {
            int rt = (nt < 2) ? (w * 2 + nt) : (8 + w * 2 + (nt - 2));
            int off = ((rt * 4 + ks) * 64 + lane) * 8;
            bfrag bh = *(const bfrag*)&Whi[off];
            bfrag bl = *(const bfrag*)&Wlo[off];
            acc[0][nt] = __builtin_amdgcn_mfma_f32_16x16x32_bf16(a0h, bh, acc[0][nt], 0, 0, 0);
            acc[0][nt] = __builtin_amdgcn_mfma_f32_16x16x32_bf16(a0h, bl, acc[0][nt], 0, 0, 0);
            acc[0][nt] = __builtin_amdgcn_mfma_f32_16x16x32_bf16(a0l, bh, acc[0][nt], 0, 0, 0);
            acc[1][nt] = __builtin_amdgcn_mfma_f32_16x16x32_bf16(a1h, bh, acc[1][nt], 0, 0, 0);
            acc[1][nt] = __builtin_amdgcn_mfma_f32_16x16x32_bf16(a1h, bl, acc[1][nt], 0, 0, 0);
            acc[1][nt] = __builtin_amdgcn_mfma_f32_16x16x32_bf16(a1l, bh, acc[1][nt], 0, 0, 0);
        }
    }
    __syncthreads();   // all Ah/Al reads done before Rf overwrite
#pragma unroll
    for (int m = 0; m < 2; ++m)
#pragma unroll
        for (int nt = 0; nt < 2; ++nt) {
            int dout = w * 32 + nt * 16 + col;
            float ba = bias[dout], bg = bias[dout + 128];
#pragma unroll
            for (int r = 0; r < 4; ++r) {
                int l = m * 16 + q * 4 + r;
                float a = acc[m][nt][r] + ba;
                float g = acc[m][nt + 2][r] + bg;
                Rf[l * 128 + dout] = a * sigmf(g);
            }
        }
    __syncthreads();
    size_t gb = l0 * Dm + (size_t)tid * 16;
#pragma unroll
    for (int i = 0; i < 4; ++i) {
        float4 r = *(float4*)&Rf[tid * 16 + i * 4];
        float4 hv = *(float4*)&h[gb + i * 4];
        hv.x += r.x; hv.y += r.y; hv.z += r.z; hv.w += r.w;
        *(float4*)&h[gb + i * 4] = hv;
    }
}

// ---------------- fused LN + FF GEMM (bf16x3 MFMA, packed weights) ----------------
__global__ __launch_bounds__(256) void s4e_ffk(const float* __restrict__ lnw,
        const float* __restrict__ lnb, const unsigned short* __restrict__ wsp,
        const float* __restrict__ b1, const float* __restrict__ b2, float* __restrict__ h) {
    __shared__ __align__(16) unsigned short smem[24576]; // Zh 8K|Zl 8K|Eh 16K|El 16K (bytes)
    unsigned short* Zh = smem;
    unsigned short* Zl = smem + 4096;
    unsigned short* Eh = smem + 8192;
    unsigned short* El = smem + 16384;
    float* Rf = (float*)smem;                 // aliases Zh+Zl (16 KB)
    const unsigned short* W1h = wsp + 65536;
    const unsigned short* W1l = wsp + 98304;
    const unsigned short* W2h = wsp + 131072;
    const unsigned short* W2l = wsp + 163840;
    size_t l0 = (size_t)blockIdx.x * 32;
    int tid = threadIdx.x;
    // ---- fused LN
    float hf[16];
    float s = 0.f, qq = 0.f;
    {
        const float* hp = h + l0 * Dm + (size_t)tid * 16;
#pragma unroll
        for (int i = 0; i < 4; ++i) {
            float4 v = *(const float4*)(hp + i * 4);
            hf[i * 4 + 0] = v.x; hf[i * 4 + 1] = v.y;
            hf[i * 4 + 2] = v.z; hf[i * 4 + 3] = v.w;
            s += v.x + v.y + v.z + v.w;
            qq += v.x * v.x + v.y * v.y + v.z * v.z + v.w * v.w;
        }
    }
    s  += __shfl_xor(s, 1);  s += __shfl_xor(s, 2);  s += __shfl_xor(s, 4);
    qq += __shfl_xor(qq, 1); qq += __shfl_xor(qq, 2); qq += __shfl_xor(qq, 4);
    float mu = s * (1.f / Dm);
    float rs = rsqrtf(qq * (1.f / Dm) - mu * mu + 1e-5f);
    int tok = tid >> 3, dc = (tid & 7) * 16;
#pragma unroll
    for (int g = 0; g < 2; ++g) {
        bfrag vh, vl;
#pragma unroll
        for (int k = 0; k < 8; ++k) {
            int d = dc + g * 8 + k;
            float v = (hf[g * 8 + k] - mu) * rs * lnw[d] + lnb[d];
            unsigned short hh, ll;
            split2(v, hh, ll);
            vh[k] = (short)hh; vl[k] = (short)ll;
        }
        int idx = (tok * 128 + dc + g * 8) ^ ((tok & 7) << 3);
        *(bfrag*)&Zh[idx] = vh;
        *(bfrag*)&Zl[idx] = vl;
    }
    __syncthreads();
    int w = tid >> 6, lane = tid & 63;
    int col = lane & 15, q = lane >> 4;
    f32x4 acc[2][4];
#pragma unroll
    for (int m = 0; m < 2; ++m)
#pragma unroll
        for (int nt = 0; nt < 4; ++nt) acc[m][nt] = (f32x4){0.f, 0.f, 0.f, 0.f};
#pragma unroll
    for (int ks = 0; ks < 4; ++ks) {
        int kb = ks * 32 + q * 8;
        int i0 = (col * 128 + kb) ^ ((col & 7) << 3);
        int i1 = ((16 + col) * 128 + kb) ^ ((col & 7) << 3);
        bfrag a0h = *(bfrag*)&Zh[i0], a0l = *(bfrag*)&Zl[i0];
        bfrag a1h = *(bfrag*)&Zh[i1], a1l = *(bfrag*)&Zl[i1];
#pragma unroll
        for (int nt = 0; nt < 4; ++nt) {
            int rt = w * 4 + nt;
            int off = ((rt * 4 + ks) * 64 + lane) * 8;
            bfrag bh = *(const bfrag*)&W1h[off];
            bfrag bl = *(const bfrag*)&W1l[off];
            acc[0][nt] = __builtin_amdgcn_mfma_f32_16x16x32_bf16(a0h, bh, acc[0][nt], 0, 0, 0);
            acc[0][nt] = __builtin_amdgcn_mfma_f32_16x16x32_bf16(a0h, bl, acc[0][nt], 0, 0, 0);
            acc[0][nt] = __builtin_amdgcn_mfma_f32_16x16x32_bf16(a0l, bh, acc[0][nt], 0, 0, 0);
            acc[1][nt] = __builtin_amdgcn_mfma_f32_16x16x32_bf16(a1h, bh, acc[1][nt], 0, 0, 0);
            acc[1][nt] = __builtin_amdgcn_mfma_f32_16x16x32_bf16(a1h, bl, acc[1][nt], 0, 0, 0);
            acc[1][nt] = __builtin_amdgcn_mfma_f32_16x16x32_bf16(a1l, bh, acc[1][nt], 0, 0, 0);
        }
    }
    // ff1 epilogue -> E
#pragma unroll
    for (int m = 0; m < 2; ++m)
#pragma unroll
        for (int nt = 0; nt < 4; ++nt) {
            int ei = w * 64 + nt * 16 + col;
            float bv = b1[ei];
#pragma unroll
            for (int r = 0; r < 4; ++r) {
                int l = m * 16 + q * 4 + r;
                float v = geluf(acc[m][nt][r] + bv);
                unsigned short hh, ll;
                split2(v, hh, ll);
                int idx = (l * 256 + ei) ^ ((l & 7) << 3);
                Eh[idx] = hh; El[idx] = ll;
            }
        }
    __syncthreads();   // E complete; Z dead from here on
    f32x4 acc2[2][2];
#pragma unroll
    for (int m = 0; m < 2; ++m)
#pragma unroll
        for (int nt = 0; nt < 2; ++nt) acc2[m][nt] = (f32x4){0.f, 0.f, 0.f, 0.f};
#pragma unroll
    for (int ks = 0; ks < 8; ++ks) {
        int kb = ks * 32 + q * 8;
        int i0 = (col * 256 + kb) ^ ((col & 7) << 3);
        int i1 = ((16 + col) * 256 + kb) ^ ((col & 7) << 3);
        bfrag a0h = *(bfrag*)&Eh[i0], a0l = *(bfrag*)&El[i0];
        bfrag a1h = *(bfrag*)&Eh[i1], a1l = *(bfrag*)&El[i1];
#pragma unroll
        for (int nt = 0; nt < 2; ++nt) {
            int rt = w * 2 + nt;
            int off = ((rt * 8 + ks) * 64 + lane) * 8;
            bfrag bh = *(const bfrag*)&W2h[off];
            bfrag bl = *(const bfrag*)&W2l[off];
            acc2[0][nt] = __builtin_amdgcn_mfma_f32_16x16x32_bf16(a0h, bh, acc2[0][nt], 0, 0, 0);
            acc2[0][nt] = __builtin_amdgcn_mfma_f32_16x16x32_bf16(a0h, bl, acc2[0][nt], 0, 0, 0);
            acc2[0][nt] = __builtin_amdgcn_mfma_f32_16x16x32_bf16(a0l, bh, acc2[0][nt], 0, 0, 0);
            acc2[1][nt] = __builtin_amdgcn_mfma_f32_16x16x32_bf16(a1h, bh, acc2[1][nt], 0, 0, 0);
            acc2[1][nt] = __builtin_amdgcn_mfma_f32_16x16x32_bf16(a1h, bl, acc2[1][nt], 0, 0, 0);
            acc2[1][nt] = __builtin_amdgcn_mfma_f32_16x16x32_bf16(a1l, bh, acc2[1][nt], 0, 0, 0);
        }
    }
    // Rf overwrites Z region (dead after barrier above)
#pragma unroll
    for (int m = 0; m < 2; ++m)
#pragma unroll
        for (int nt = 0; nt < 2; ++nt) {
            int dout = w * 32 + nt * 16 + col;
            float bv = b2[dout];
#pragma unroll
            for (int r = 0; r < 4; ++r) {
                int l = m * 16 + q * 4 + r;
                Rf[l * 128 + dout] = acc2[m][nt][r] + bv;
            }
        }
    __syncthreads();
    size_t gb = l0 * Dm + (size_t)tid * 16;
#pragma unroll
    for (int i = 0; i < 4; ++i) {
        float4 r = *(float4*)&Rf[tid * 16 + i * 4];
        float4 o;
        o.x = hf[i * 4 + 0] + r.x; o.y = hf[i * 4 + 1] + r.y;
        o.z = hf[i * 4 + 2] + r.z; o.w = hf[i * 4 + 3] + r.w;
        *(float4*)&h[gb + i * 4] = o;
    }
}

// ---------------- head ----------------
__global__ void s4e_head(const float* __restrict__ h, const float* __restrict__ hw,
                         const float* __restrict__ hb, int* __restrict__ out) {
    __shared__ float logit[Bb][NCl];
    int tid = threadIdx.x;
    int b = tid >> 4, c = tid & 15;
    const float* hp = h + ((size_t)b * Ls + (Ls - 1)) * Dm;
    float acc = hb[c];
    for (int d = 0; d < Dm; ++d) acc = fmaf(hp[d], hw[c * Dm + d], acc);
    logit[b][c] = acc;
    __syncthreads();
    if (c == 0) {
        float best = logit[b][0]; int bi = 0;
#pragma unroll
        for (int k = 1; k < NCl; ++k) {
            float v = logit[b][k];
            if (v > best) { best = v; bi = k; }
        }
        out[b] = bi;
    }
}

extern "C" void kernel_launch(void* const* d_in, const int* in_sizes, int n_in,
                              void* d_out, int out_size, void* d_ws, size_t ws_size,
                              hipStream_t stream) {
    const float* x        = (const float*)d_in[0];
    const float* conv_w   = (const float*)d_in[1];
    const float* conv_b   = (const float*)d_in[2];
    const float* s4_ln_w  = (const float*)d_in[3];
    const float* s4_ln_b  = (const float*)d_in[4];
    const float* s4_logdt = (const float*)d_in[5];
    const float* s4_lAr   = (const float*)d_in[6];
    const float* s4_Aim   = (const float*)d_in[7];
    const float* s4_Cre   = (const float*)d_in[8];
    const float* s4_Cim   = (const float*)d_in[9];
    const float* s4_D     = (const float*)d_in[10];
    const float* s4_ow    = (const float*)d_in[11];
    const float* s4_ob    = (const float*)d_in[12];
    const float* ff_ln_w  = (const float*)d_in[13];
    const float* ff_ln_b  = (const float*)d_in[14];
    const float* ff_w1    = (const float*)d_in[15];
    const float* ff_b1    = (const float*)d_in[16];
    const float* ff_w2    = (const float*)d_in[17];
    const float* ff_b2    = (const float*)d_in[18];
    const float* head_w   = (const float*)d_in[19];
    const float* head_b   = (const float*)d_in[20];
    int* out = (int*)d_out;

    float* ws = (float*)d_ws;
    float* h  = ws;                                           // 64 MB
    float2* stats = (float2*)(ws + 16777216);                 // 1 MB
    unsigned short* acth = (unsigned short*)(ws + 33554432);  // 32 MB
    unsigned short* actl = (unsigned short*)(ws + 41943040);  // 32 MB
    float2* send  = (float2*)(ws + 50331648);                 // 33.5 MB (in-place prefix)
    float2* wv    = (float2*)(ws + 58720256);
    float2* wp    = (float2*)(ws + 58728448);
    float2* Cc    = (float2*)(ws + 58736640);
    unsigned short* wsp = (unsigned short*)(ws + 58744832);

    s4e_conv<<<BL * 32 / 256, 256, 0, stream>>>(x, conv_w, conv_b, h);
    for (int i = 0; i < NBK; ++i) {
        s4e_setup<<<1, 128, 0, stream>>>(s4_logdt + i * Dm, s4_lAr + i * Dm * Nst,
                                         s4_Aim + i * Dm * Nst, s4_Cre + i * Dm * Nst,
                                         s4_Cim + i * Dm * Nst, wv, wp, Cc);
        s4e_wsplit<<<48, 256, 0, stream>>>(s4_ow + i * Em * Dm, ff_w1 + i * Em * Dm,
                                           ff_w2 + i * Dm * Em, wsp);
        s4e_lnstat<<<BL / 64, 256, 0, stream>>>(h, stats);
        s4e_s1<<<1024, 256, 0, stream>>>(h, stats, s4_ln_w + i * Dm, s4_ln_b + i * Dm, wv, send);
        s4e_s2<<<256, 256, 0, stream>>>(wp, send);
        s4e_s3<<<1024, 256, 0, stream>>>(h, stats, s4_ln_w + i * Dm, s4_ln_b + i * Dm,
                                         wv, Cc, send, s4_D + i * Dm, acth, actl);
        s4e_outproj<<<BL / 32, 256, 0, stream>>>(acth, actl, wsp, s4_ob + i * Em, h);
        s4e_ffk<<<BL / 32, 256, 0, stream>>>(ff_ln_w + i * Dm, ff_ln_b + i * Dm, wsp,
                                             ff_b1 + i * Em, ff_b2 + i * Dm, h);
    }
    s4e_head<<<1, 256, 0, stream>>>(h, head_w, head_b, out);
}

// Round 11
// 2131.529 us; speedup vs baseline: 2.4844x; 1.1363x over previous
//
#include <hip/hip_runtime.h>
#include <math.h>

#define Bb 16
#define Ls 8192
#define Dm 128
#define NBK 6
#define Nst 32
#define NCl 16
#define Em 256
#define LC 128
#define NCH 64
#define BL (Bb*Ls)

typedef __attribute__((ext_vector_type(8))) short bfrag;   // 8 bf16 (4 VGPRs)
typedef __attribute__((ext_vector_type(4))) float f32x4;

// fast gelu (tanh-approx form, via exp2/rcp; branch-free)
__device__ __forceinline__ float geluf(float x) {
    float t = x * x;
    float g = x * fmaf(0.102952207f, t, 2.30234547f);   // 2u*log2(e)
    float e = exp2f(-g);
    return x * __builtin_amdgcn_rcpf(1.f + e);
}
__device__ __forceinline__ float sigmf(float x) {
    return __builtin_amdgcn_rcpf(1.f + exp2f(-1.44269504f * x));
}

__device__ __forceinline__ unsigned short bf16r(float x) {
    unsigned u = __float_as_uint(x);
    return (unsigned short)((u + 0x7FFFu + ((u >> 16) & 1u)) >> 16);
}
__device__ __forceinline__ void split2(float x, unsigned short& h, unsigned short& l) {
    h = bf16r(x);
    float hf = __uint_as_float(((unsigned)h) << 16);
    l = bf16r(x - hf);
}

// ---------------- conv: h[b,l,d] (token-major) ----------------
__global__ void s4e_conv(const float* __restrict__ x, const float* __restrict__ cw,
                         const float* __restrict__ cb, float* __restrict__ h) {
    int tid = blockIdx.x * 256 + threadIdx.x;     // B*L*32
    int d4 = tid & 31;
    int t = tid >> 5;
    int l = t & (Ls - 1);
    int b = t >> 13;
    const float* xb = x + (size_t)b * Ls;
    float xs[5];
#pragma unroll
    for (int k = 0; k < 5; ++k) {
        int p = l + k - 2;
        xs[k] = (p >= 0 && p < Ls) ? xb[p] : 0.f;
    }
    float4 acc;
    float* ap = &acc.x;
#pragma unroll
    for (int j = 0; j < 4; ++j) {
        int d = d4 * 4 + j;
        float a = cb[d];
#pragma unroll
        for (int k = 0; k < 5; ++k) a = fmaf(cw[d * 5 + k], xs[k], a);
        ap[j] = a;
    }
    *(float4*)&h[(size_t)t * Dm + d4 * 4] = acc;
}

// ---------------- LN stats: per-token mu, rs ----------------
__global__ void s4e_lnstat(const float* __restrict__ h, float2* __restrict__ stats) {
    int tid = threadIdx.x;
    int t = blockIdx.x * 64 + (tid >> 2);
    int sub = tid & 3;
    const float* hp = h + (size_t)t * Dm + sub * 32;
    float s = 0.f, q = 0.f;
#pragma unroll
    for (int i = 0; i < 8; ++i) {
        float4 v = *(const float4*)(hp + i * 4);
        s += v.x + v.y + v.z + v.w;
        q += v.x * v.x + v.y * v.y + v.z * v.z + v.w * v.w;
    }
    s += __shfl_xor(s, 1); s += __shfl_xor(s, 2);
    q += __shfl_xor(q, 1); q += __shfl_xor(q, 2);
    float mu = s * (1.f / Dm);
    float rs = rsqrtf(q * (1.f / Dm) - mu * mu + 1e-5f);
    if (sub == 0) stats[t] = make_float2(mu, rs);
}

// ---------------- S4 params for ALL layers: [n][d], wp = w^LC, Cc pre-doubled ----------------
__global__ void s4e_setup6(const float* __restrict__ log_dt, const float* __restrict__ lAr,
                           const float* __restrict__ Aim, const float* __restrict__ Cre,
                           const float* __restrict__ Cim, float2* __restrict__ wv6,
                           float2* __restrict__ wp6, float2* __restrict__ Cc6) {
    int i = blockIdx.x;          // layer
    int d = threadIdx.x;
    const float* ld  = log_dt + i * Dm;
    const float* la  = lAr + i * Dm * Nst;
    const float* ai  = Aim + i * Dm * Nst;
    const float* cre = Cre + i * Dm * Nst;
    const float* cim = Cim + i * Dm * Nst;
    float2* wv = wv6 + i * (Nst * Dm);
    float2* wp = wp6 + i * (Nst * Dm);
    float2* Cc = Cc6 + i * (Nst * Dm);
    float dt = expf(ld[d]);
    for (int n = 0; n < Nst; ++n) {
        int id = d * Nst + n;
        float Ar = -expf(la[id]);
        float Ai = ai[id];
        float xr = dt * Ar, xi = dt * Ai;
        float er = expf(xr);
        float wr = er * cosf(xi), wi = er * sinf(xi);
        wv[n * Dm + d] = make_float2(wr, wi);
        float den = Ar * Ar + Ai * Ai;
        float inv = 1.f / den;
        float fr = ((wr - 1.f) * Ar + wi * Ai) * inv;
        float fi = (wi * Ar - (wr - 1.f) * Ai) * inv;
        Cc[n * Dm + d] = make_float2(2.f * (cre[id] * fr - cim[id] * fi),
                                     2.f * (cre[id] * fi + cim[id] * fr));
        float pr = wr, pi = wi;
#pragma unroll
        for (int sq = 0; sq < 7; ++sq) {     // w^128 = w^LC
            float nr = pr * pr - pi * pi;
            float ni = 2.f * pr * pi;
            pr = nr; pi = ni;
        }
        wp[n * Dm + d] = make_float2(pr, pi);
    }
}

// ---------------- weight split + MFMA-fragment pack, ALL layers ----------------
// packed[((rt*KT + kt)*64 + lane)*8 + j] = W[rt*16 + (lane&15)][kt*32 + (lane>>4)*8 + j]
__global__ void s4e_wsplit6(const float* __restrict__ ow, const float* __restrict__ w1,
                            const float* __restrict__ w2, unsigned short* __restrict__ base0) {
    int idx = blockIdx.x * 256 + threadIdx.x;   // 6 layers * 12288 groups
    int layer = idx / 12288;
    int r = idx - layer * 12288;
    int mat = r >> 12;
    int g = r & 4095;
    int lane = g & 63;
    int fid = g >> 6;
    int col = lane & 15, q = lane >> 4;
    unsigned short* base = base0 + layer * 196608;
    const float* src;
    unsigned short *dh, *dl_;
    int rt, kt, K;
    if (mat == 0)      { src = ow + layer * 32768; K = 128; dh = base;          dl_ = base + 32768;  rt = fid >> 2; kt = fid & 3; }
    else if (mat == 1) { src = w1 + layer * 32768; K = 128; dh = base + 65536;  dl_ = base + 98304;  rt = fid >> 2; kt = fid & 3; }
    else               { src = w2 + layer * 32768; K = 256; dh = base + 131072; dl_ = base + 163840; rt = fid >> 3; kt = fid & 7; }
    int row = rt * 16 + col;
    int k0 = kt * 32 + q * 8;
    const float* sp = src + row * K + k0;
    bfrag vh, vl;
#pragma unroll
    for (int j = 0; j < 8; ++j) {
        unsigned short hh, ll;
        split2(sp[j], hh, ll);
        vh[j] = (short)hh; vl[j] = (short)ll;
    }
    *(bfrag*)&dh[g * 8] = vh;
    *(bfrag*)&dl_[g * 8] = vl;
}

// ---------------- S1: per-chunk end states, inline LN, LDS stats, 4-deep loads ----------------
__global__ __launch_bounds__(256) void s4e_s1(const float* __restrict__ h,
        const float2* __restrict__ stats, const float* __restrict__ lnw,
        const float* __restrict__ lnb, const float2* __restrict__ wv,
        float2* __restrict__ send) {
    __shared__ float2 stl[LC];
    int tid = threadIdx.x;
    int blk = blockIdx.x;            // b*NCH + c
    int c = blk & (NCH - 1);
    int b = blk >> 6;
    int dl = tid & 31;
    int m  = (tid >> 5) & 1;
    int dh = tid >> 6;
    int d  = dh * 32 + dl;
    int n0 = m * 16;
    const float2* st = stats + (size_t)b * Ls + c * LC;
    if (tid < LC) stl[tid] = st[tid];
    float wr[16], wi[16], sr[16], si[16];
#pragma unroll
    for (int k = 0; k < 16; ++k) {
        float2 t = wv[(n0 + k) * Dm + d];
        wr[k] = t.x; wi[k] = t.y; sr[k] = 0.f; si[k] = 0.f;
    }
    float wd = lnw[d], bd = lnb[d];
    const float* hp = h + ((size_t)b * Ls + c * LC) * Dm + d;
    __syncthreads();
#pragma unroll 1
    for (int j = 0; j < LC; j += 4) {
        float hv[4];
#pragma unroll
        for (int u = 0; u < 4; ++u) hv[u] = hp[(size_t)(j + u) * Dm];
        float zv[4];
#pragma unroll
        for (int u = 0; u < 4; ++u) {
            float2 sj = stl[j + u];
            zv[u] = (hv[u] - sj.x) * sj.y * wd + bd;
        }
#pragma unroll
        for (int u = 0; u < 4; ++u) {
            float z = zv[u];
#pragma unroll
            for (int k = 0; k < 16; ++k) {
                float t = fmaf(-wi[k], si[k], z);
                float nr = fmaf(wr[k], sr[k], t);
                float ni = fmaf(wi[k], sr[k], wr[k] * si[k]);
                sr[k] = nr; si[k] = ni;
            }
        }
    }
    float2* o = send + ((size_t)(b * NCH + c) * Nst + n0) * Dm + d;
#pragma unroll
    for (int k = 0; k < 16; ++k) o[k * Dm] = make_float2(sr[k], si[k]);
}

// ---------------- S2: in-place cross-chunk prefix ----------------
__global__ void s4e_s2(const float2* __restrict__ wp, float2* __restrict__ s) {
    int tid = blockIdx.x * 256 + threadIdx.x;   // B*Nst*Dm = 65536
    int d = tid & 127;
    int n = (tid >> 7) & 31;
    int b = tid >> 12;
    float2 W = wp[n * Dm + d];
    float Sr = 0.f, Si = 0.f;
    size_t base = ((size_t)(b * NCH) * Nst + n) * Dm + d;
    size_t cs = (size_t)Nst * Dm;
    for (int c0 = 0; c0 < NCH; c0 += 8) {
        float2 E[8];
#pragma unroll
        for (int k = 0; k < 8; ++k) E[k] = s[base + (size_t)(c0 + k) * cs];
#pragma unroll
        for (int k = 0; k < 8; ++k) {
            float2 o = make_float2(Sr, Si);
            float nr = fmaf(W.x, Sr, fmaf(-W.y, Si, E[k].x));
            float ni = fmaf(W.x, Si, fmaf(W.y, Sr, E[k].y));
            Sr = nr; Si = ni;
            s[base + (size_t)(c0 + k) * cs] = o;
        }
    }
}

// ---------------- S3: re-scan, inline LN, LDS stats, 4-deep loads, act bf16 hi/lo ----------------
__global__ __launch_bounds__(256) void s4e_s3(const float* __restrict__ h,
        const float2* __restrict__ stats, const float* __restrict__ lnw,
        const float* __restrict__ lnb, const float2* __restrict__ wv,
        const float2* __restrict__ Cc, const float2* __restrict__ sinit,
        const float* __restrict__ Dsk,
        unsigned short* __restrict__ acth, unsigned short* __restrict__ actl) {
    __shared__ float2 stl[LC];
    int tid = threadIdx.x;
    int blk = blockIdx.x;
    int c = blk & (NCH - 1);
    int b = blk >> 6;
    int dl = tid & 31;
    int m  = (tid >> 5) & 1;
    int dh = tid >> 6;
    int d  = dh * 32 + dl;
    int n0 = m * 16;
    const float2* st = stats + (size_t)b * Ls + c * LC;
    if (tid < LC) stl[tid] = st[tid];
    float wr[16], wi[16], cr[16], ci[16], sr[16], si[16];
    const float2* s0 = sinit + ((size_t)(b * NCH + c) * Nst + n0) * Dm + d;
#pragma unroll
    for (int k = 0; k < 16; ++k) {
        float2 t = wv[(n0 + k) * Dm + d];  wr[k] = t.x; wi[k] = t.y;
        float2 cc = Cc[(n0 + k) * Dm + d]; cr[k] = cc.x; ci[k] = cc.y;
        float2 ss = s0[k * Dm];            sr[k] = ss.x; si[k] = ss.y;
    }
    float wd = lnw[d], bd = lnb[d];
    float Dv = Dsk[d];
    size_t ib = ((size_t)b * Ls + c * LC) * Dm + d;
    __syncthreads();
#pragma unroll 1
    for (int j = 0; j < LC; j += 4) {
        float hv[4];
#pragma unroll
        for (int u = 0; u < 4; ++u) hv[u] = h[ib + (size_t)(j + u) * Dm];
        float zv[4];
#pragma unroll
        for (int u = 0; u < 4; ++u) {
            float2 sj = stl[j + u];
            zv[u] = (hv[u] - sj.x) * sj.y * wd + bd;
        }
#pragma unroll
        for (int u = 0; u < 4; ++u) {
            float z = zv[u];
            float acc = 0.f;
#pragma unroll
            for (int k = 0; k < 16; ++k) {
                float t = fmaf(-wi[k], si[k], z);
                float nr = fmaf(wr[k], sr[k], t);
                float ni = fmaf(wi[k], sr[k], wr[k] * si[k]);
                sr[k] = nr; si[k] = ni;
                acc = fmaf(cr[k], nr, acc);
                acc = fmaf(-ci[k], ni, acc);
            }
            acc += __shfl_xor(acc, 32);
            if (m == 0) {
                float av = geluf(fmaf(Dv, z, acc));
                unsigned short hh, ll;
                split2(av, hh, ll);
                acth[ib + (size_t)(j + u) * Dm] = hh;
                actl[ib + (size_t)(j + u) * Dm] = ll;
            }
        }
    }
}

// ---------------- outproj GEMM (bf16x3 MFMA, packed weights) + GLU ----------------
__global__ __launch_bounds__(256) void s4e_outproj(const unsigned short* __restrict__ acth,
        const unsigned short* __restrict__ actl, const unsigned short* __restrict__ wsp,
        const float* __restrict__ bias, float* __restrict__ h) {
    __shared__ __align__(16) unsigned short smem[8192];   // Ah 8K | Al 8K ; Rf aliases 16K
    unsigned short* Ah = smem;
    unsigned short* Al = smem + 4096;
    float* Rf = (float*)smem;
    const unsigned short* Whi = wsp;
    const unsigned short* Wlo = wsp + 32768;
    size_t l0 = (size_t)blockIdx.x * 32;
    int tid = threadIdx.x;
    {
        const unsigned short* gh = acth + l0 * Dm;
        const unsigned short* gl = actl + l0 * Dm;
        for (int i = tid * 8; i < 32 * 128; i += 2048) {
            int r = i >> 7;
            int di = i ^ ((r & 7) << 3);
            *(bfrag*)&Ah[di] = *(const bfrag*)&gh[i];
            *(bfrag*)&Al[di] = *(const bfrag*)&gl[i];
        }
    }
    __syncthreads();
    int w = tid >> 6, lane = tid & 63;
    int col = lane & 15, q = lane >> 4;
    f32x4 acc[2][4];
#pragma unroll
    for (int m = 0; m < 2; ++m)
#pragma unroll
        for (int nt = 0; nt < 4; ++nt) acc[m][nt] = (f32x4){0.f, 0.f, 0.f, 0.f};
#pragma unroll
    for (int ks = 0; ks < 4; ++ks) {
        int kb = ks * 32 + q * 8;
        int i0 = (col * 128 + kb) ^ ((col & 7) << 3);
        int i1 = ((16 + col) * 128 + kb) ^ ((col & 7) << 3);
        bfrag a0h = *(bfrag*)&Ah[i0], a0l = *(bfrag*)&Al[i0];
        bfrag a1h = *(bfrag*)&Ah[i1], a1l = *(bfrag*)&Al[i1];
#pragma unroll
        for (int nt = 0; nt < 4; ++nt) {
            int rt = (nt < 2) ? (w * 2 + nt) : (8 + w * 2 + (nt - 2));
            int off = ((rt * 4 + ks) * 64 + lane) * 8;
            bfrag bh = *(const bfrag*)&Whi[off];
            bfrag bl = *(const bfrag*)&Wlo[off];
            acc[0][nt] = __builtin_amdgcn_mfma_f32_16x16x32_bf16(a0h, bh, acc[0][nt], 0, 0, 0);
            acc[0][nt] = __builtin_amdgcn_mfma_f32_16x16x32_bf16(a0h, bl, acc[0][nt], 0, 0, 0);
            acc[0][nt] = __builtin_amdgcn_mfma_f32_16x16x32_bf16(a0l, bh, acc[0][nt], 0, 0, 0);
            acc[1][nt] = __builtin_amdgcn_mfma_f32_16x16x32_bf16(a1h, bh, acc[1][nt], 0, 0, 0);
            acc[1][nt] = __builtin_amdgcn_mfma_f32_16x16x32_bf16(a1h, bl, acc[1][nt], 0, 0, 0);
            acc[1][nt] = __builtin_amdgcn_mfma_f32_16x16x32_bf16(a1l, bh, acc[1][nt], 0, 0, 0);
        }
    }
    __syncthreads();   // all Ah/Al reads done before Rf overwrite
#pragma unroll
    for (int m = 0; m < 2; ++m)
#pragma unroll
        for (int nt = 0; nt < 2; ++nt) {
            int dout = w * 32 + nt * 16 + col;
            float ba = bias[dout], bg = bias[dout + 128];
#pragma unroll
            for (int r = 0; r < 4; ++r) {
                int l = m * 16 + q * 4 + r;
                float a = acc[m][nt][r] + ba;
                float g = acc[m][nt + 2][r] + bg;
                Rf[l * 128 + dout] = a * sigmf(g);
            }
        }
    __syncthreads();
    size_t gb = l0 * Dm + (size_t)tid * 16;
#pragma unroll
    for (int i = 0; i < 4; ++i) {
        float4 r = *(float4*)&Rf[tid * 16 + i * 4];
        float4 hv = *(float4*)&h[gb + i * 4];
        hv.x += r.x; hv.y += r.y; hv.z += r.z; hv.w += r.w;
        *(float4*)&h[gb + i * 4] = hv;
    }
}

// ---------------- fused LN + FF GEMM (bf16x3 MFMA, packed weights) ----------------
__global__ __launch_bounds__(256) void s4e_ffk(const float* __restrict__ lnw,
        const float* __restrict__ lnb, const unsigned short* __restrict__ wsp,
        const float* __restrict__ b1, const float* __restrict__ b2, float* __restrict__ h) {
    __shared__ __align__(16) unsigned short smem[24576]; // Zh 8K|Zl 8K|Eh 16K|El 16K (bytes)
    unsigned short* Zh = smem;
    unsigned short* Zl = smem + 4096;
    unsigned short* Eh = smem + 8192;
    unsigned short* El = smem + 16384;
    float* Rf = (float*)smem;                 // aliases Zh+Zl (16 KB)
    const unsigned short* W1h = wsp + 65536;
    const unsigned short* W1l = wsp + 98304;
    const unsigned short* W2h = wsp + 131072;
    const unsigned short* W2l = wsp + 163840;
    size_t l0 = (size_t)blockIdx.x * 32;
    int tid = threadIdx.x;
    // ---- fused LN
    float hf[16];
    float s = 0.f, qq = 0.f;
    {
        const float* hp = h + l0 * Dm + (size_t)tid * 16;
#pragma unroll
        for (int i = 0; i < 4; ++i) {
            float4 v = *(const float4*)(hp + i * 4);
            hf[i * 4 + 0] = v.x; hf[i * 4 + 1] = v.y;
            hf[i * 4 + 2] = v.z; hf[i * 4 + 3] = v.w;
            s += v.x + v.y + v.z + v.w;
            qq += v.x * v.x + v.y * v.y + v.z * v.z + v.w * v.w;
        }
    }
    s  += __shfl_xor(s, 1);  s += __shfl_xor(s, 2);  s += __shfl_xor(s, 4);
    qq += __shfl_xor(qq, 1); qq += __shfl_xor(qq, 2); qq += __shfl_xor(qq, 4);
    float mu = s * (1.f / Dm);
    float rs = rsqrtf(qq * (1.f / Dm) - mu * mu + 1e-5f);
    int tok = tid >> 3, dc = (tid & 7) * 16;
#pragma unroll
    for (int g = 0; g < 2; ++g) {
        bfrag vh, vl;
#pragma unroll
        for (int k = 0; k < 8; ++k) {
            int d = dc + g * 8 + k;
            float v = (hf[g * 8 + k] - mu) * rs * lnw[d] + lnb[d];
            unsigned short hh, ll;
            split2(v, hh, ll);
            vh[k] = (short)hh; vl[k] = (short)ll;
        }
        int idx = (tok * 128 + dc + g * 8) ^ ((tok & 7) << 3);
        *(bfrag*)&Zh[idx] = vh;
        *(bfrag*)&Zl[idx] = vl;
    }
    __syncthreads();
    int w = tid >> 6, lane = tid & 63;
    int col = lane & 15, q = lane >> 4;
    f32x4 acc[2][4];
#pragma unroll
    for (int m = 0; m < 2; ++m)
#pragma unroll
        for (int nt = 0; nt < 4; ++nt) acc[m][nt] = (f32x4){0.f, 0.f, 0.f, 0.f};
#pragma unroll
    for (int ks = 0; ks < 4; ++ks) {
        int kb = ks * 32 + q * 8;
        int i0 = (col * 128 + kb) ^ ((col & 7) << 3);
        int i1 = ((16 + col) * 128 + kb) ^ ((col & 7) << 3);
        bfrag a0h = *(bfrag*)&Zh[i0], a0l = *(bfrag*)&Zl[i0];
        bfrag a1h = *(bfrag*)&Zh[i1], a1l = *(bfrag*)&Zl[i1];
#pragma unroll
        for (int nt = 0; nt < 4; ++nt) {
            int rt = w * 4 + nt;
            int off = ((rt * 4 + ks) * 64 + lane) * 8;
            bfrag bh = *(const bfrag*)&W1h[off];
            bfrag bl = *(const bfrag*)&W1l[off];
            acc[0][nt] = __builtin_amdgcn_mfma_f32_16x16x32_bf16(a0h, bh, acc[0][nt], 0, 0, 0);
            acc[0][nt] = __builtin_amdgcn_mfma_f32_16x16x32_bf16(a0h, bl, acc[0][nt], 0, 0, 0);
            acc[0][nt] = __builtin_amdgcn_mfma_f32_16x16x32_bf16(a0l, bh, acc[0][nt], 0, 0, 0);
            acc[1][nt] = __builtin_amdgcn_mfma_f32_16x16x32_bf16(a1h, bh, acc[1][nt], 0, 0, 0);
            acc[1][nt] = __builtin_amdgcn_mfma_f32_16x16x32_bf16(a1h, bl, acc[1][nt], 0, 0, 0);
            acc[1][nt] = __builtin_amdgcn_mfma_f32_16x16x32_bf16(a1l, bh, acc[1][nt], 0, 0, 0);
        }
    }
    // ff1 epilogue -> E
#pragma unroll
    for (int m = 0; m < 2; ++m)
#pragma unroll
        for (int nt = 0; nt < 4; ++nt) {
            int ei = w * 64 + nt * 16 + col;
            float bv = b1[ei];
#pragma unroll
            for (int r = 0; r < 4; ++r) {
                int l = m * 16 + q * 4 + r;
                float v = geluf(acc[m][nt][r] + bv);
                unsigned short hh, ll;
                split2(v, hh, ll);
                int idx = (l * 256 + ei) ^ ((l & 7) << 3);
                Eh[idx] = hh; El[idx] = ll;
            }
        }
    __syncthreads();   // E complete; Z dead from here on
    f32x4 acc2[2][2];
#pragma unroll
    for (int m = 0; m < 2; ++m)
#pragma unroll
        for (int nt = 0; nt < 2; ++nt) acc2[m][nt] = (f32x4){0.f, 0.f, 0.f, 0.f};
#pragma unroll
    for (int ks = 0; ks < 8; ++ks) {
        int kb = ks * 32 + q * 8;
        int i0 = (col * 256 + kb) ^ ((col & 7) << 3);
        int i1 = ((16 + col) * 256 + kb) ^ ((col & 7) << 3);
        bfrag a0h = *(bfrag*)&Eh[i0], a0l = *(bfrag*)&El[i0];
        bfrag a1h = *(bfrag*)&Eh[i1], a1l = *(bfrag*)&El[i1];
#pragma unroll
        for (int nt = 0; nt < 2; ++nt) {
            int rt = w * 2 + nt;
            int off = ((rt * 8 + ks) * 64 + lane) * 8;
            bfrag bh = *(const bfrag*)&W2h[off];
            bfrag bl = *(const bfrag*)&W2l[off];
            acc2[0][nt] = __builtin_amdgcn_mfma_f32_16x16x32_bf16(a0h, bh, acc2[0][nt], 0, 0, 0);
            acc2[0][nt] = __builtin_amdgcn_mfma_f32_16x16x32_bf16(a0h, bl, acc2[0][nt], 0, 0, 0);
            acc2[0][nt] = __builtin_amdgcn_mfma_f32_16x16x32_bf16(a0l, bh, acc2[0][nt], 0, 0, 0);
            acc2[1][nt] = __builtin_amdgcn_mfma_f32_16x16x32_bf16(a1h, bh, acc2[1][nt], 0, 0, 0);
            acc2[1][nt] = __builtin_amdgcn_mfma_f32_16x16x32_bf16(a1h, bl, acc2[1][nt], 0, 0, 0);
            acc2[1][nt] = __builtin_amdgcn_mfma_f32_16x16x32_bf16(a1l, bh, acc2[1][nt], 0, 0, 0);
        }
    }
    // Rf overwrites Z region (dead after barrier above)
#pragma unroll
    for (int m = 0; m < 2; ++m)
#pragma unroll
        for (int nt = 0; nt < 2; ++nt) {
            int dout = w * 32 + nt * 16 + col;
            float bv = b2[dout];
#pragma unroll
            for (int r = 0; r < 4; ++r) {
                int l = m * 16 + q * 4 + r;
                Rf[l * 128 + dout] = acc2[m][nt][r] + bv;
            }
        }
    __syncthreads();
    size_t gb = l0 * Dm + (size_t)tid * 16;
#pragma unroll
    for (int i = 0; i < 4; ++i) {
        float4 r = *(float4*)&Rf[tid * 16 + i * 4];
        float4 o;
        o.x = hf[i * 4 + 0] + r.x; o.y = hf[i * 4 + 1] + r.y;
        o.z = hf[i * 4 + 2] + r.z; o.w = hf[i * 4 + 3] + r.w;
        *(float4*)&h[gb + i * 4] = o;
    }
}

// ---------------- head ----------------
__global__ void s4e_head(const float* __restrict__ h, const float* __restrict__ hw,
                         const float* __restrict__ hb, int* __restrict__ out) {
    __shared__ float logit[Bb][NCl];
    int tid = threadIdx.x;
    int b = tid >> 4, c = tid & 15;
    const float* hp = h + ((size_t)b * Ls + (Ls - 1)) * Dm;
    float acc = hb[c];
    for (int d = 0; d < Dm; ++d) acc = fmaf(hp[d], hw[c * Dm + d], acc);
    logit[b][c] = acc;
    __syncthreads();
    if (c == 0) {
        float best = logit[b][0]; int bi = 0;
#pragma unroll
        for (int k = 1; k < NCl; ++k) {
            float v = logit[b][k];
            if (v > best) { best = v; bi = k; }
        }
        out[b] = bi;
    }
}

extern "C" void kernel_launch(void* const* d_in, const int* in_sizes, int n_in,
                              void* d_out, int out_size, void* d_ws, size_t ws_size,
                              hipStream_t stream) {
    const float* x        = (const float*)d_in[0];
    const float* conv_w   = (const float*)d_in[1];
    const float* conv_b   = (const float*)d_in[2];
    const float* s4_ln_w  = (const float*)d_in[3];
    const float* s4_ln_b  = (const float*)d_in[4];
    const float* s4_logdt = (const float*)d_in[5];
    const float* s4_lAr   = (const float*)d_in[6];
    const float* s4_Aim   = (const float*)d_in[7];
    const float* s4_Cre   = (const float*)d_in[8];
    const float* s4_Cim   = (const float*)d_in[9];
    const float* s4_D     = (const float*)d_in[10];
    const float* s4_ow    = (const float*)d_in[11];
    const float* s4_ob    = (const float*)d_in[12];
    const float* ff_ln_w  = (const float*)d_in[13];
    const float* ff_ln_b  = (const float*)d_in[14];
    const float* ff_w1    = (const float*)d_in[15];
    const float* ff_b1    = (const float*)d_in[16];
    const float* ff_w2    = (const float*)d_in[17];
    const float* ff_b2    = (const float*)d_in[18];
    const float* head_w   = (const float*)d_in[19];
    const float* head_b   = (const float*)d_in[20];
    int* out = (int*)d_out;

    float* ws = (float*)d_ws;
    float* h  = ws;                                           // 64 MB
    float2* stats = (float2*)(ws + 16777216);                 // 1 MB
    // free gap from old z buffer reused for per-layer param caches:
    float2* wv6 = (float2*)(ws + 17039360);                   // 6*4096 float2
    float2* wp6 = (float2*)(ws + 17088512);
    float2* Cc6 = (float2*)(ws + 17137664);
    unsigned short* wsp6 = (unsigned short*)(ws + 17186816);  // 6*196608 ushort
    unsigned short* acth = (unsigned short*)(ws + 33554432);  // 32 MB
    unsigned short* actl = (unsigned short*)(ws + 41943040);  // 32 MB
    float2* send  = (float2*)(ws + 50331648);                 // 33.5 MB (in-place prefix)

    s4e_conv<<<BL * 32 / 256, 256, 0, stream>>>(x, conv_w, conv_b, h);
    s4e_setup6<<<NBK, 128, 0, stream>>>(s4_logdt, s4_lAr, s4_Aim, s4_Cre, s4_Cim,
                                        wv6, wp6, Cc6);
    s4e_wsplit6<<<288, 256, 0, stream>>>(s4_ow, ff_w1, ff_w2, wsp6);
    for (int i = 0; i < NBK; ++i) {
        float2* wv = wv6 + i * (Nst * Dm);
        float2* wp = wp6 + i * (Nst * Dm);
        float2* Cc = Cc6 + i * (Nst * Dm);
        unsigned short* wsp = wsp6 + i * 196608;
        s4e_lnstat<<<BL / 64, 256, 0, stream>>>(h, stats);
        s4e_s1<<<1024, 256, 0, stream>>>(h, stats, s4_ln_w + i * Dm, s4_ln_b + i * Dm, wv, send);
        s4e_s2<<<256, 256, 0, stream>>>(wp, send);
        s4e_s3<<<1024, 256, 0, stream>>>(h, stats, s4_ln_w + i * Dm, s4_ln_b + i * Dm,
                                         wv, Cc, send, s4_D + i * Dm, acth, actl);
        s4e_outproj<<<BL / 32, 256, 0, stream>>>(acth, actl, wsp, s4_ob + i * Em, h);
        s4e_ffk<<<BL / 32, 256, 0, stream>>>(ff_ln_w + i * Dm, ff_ln_b + i * Dm, wsp,
                                             ff_b1 + i * Em, ff_b2 + i * Dm, h);
    }
    s4e_head<<<1, 256, 0, stream>>>(h, head_w, head_b, out);
}